// Round 1
// baseline (342.088 us; speedup 1.0000x reference)
//
#include <hip/hip_runtime.h>

#define N_NODES 50000
#define N_EDGES 800000
#define IN_C    128
#define HID     64
#define NUM_G   256
#define OUT_C   8

// ---------------------------------------------------------------- init
__global__ void k_init(int* __restrict__ deg, float* __restrict__ pooled,
                       int* __restrict__ cnts) {
    int i = blockIdx.x * blockDim.x + threadIdx.x;
    if (i < N_NODES) deg[i] = 1;              // self-loop contributes 1
    if (i < NUM_G * HID) pooled[i] = 0.f;
    if (i < NUM_G) cnts[i] = 0;
}

// ---------------------------------------------------------------- x @ W
// block = 256 threads = 4 rows x 64 hid. x rows + W staged in LDS.
__global__ void k_lin(const float* __restrict__ x, const float* __restrict__ W,
                      float* __restrict__ xlin) {
    __shared__ float xs[4 * IN_C];        // 2 KiB
    __shared__ float Ws[IN_C * HID];      // 32 KiB
    const int tid  = threadIdx.x;
    const int row0 = blockIdx.x * 4;

    // 4 rows of x = 512 floats: each thread loads one float2
    ((float2*)xs)[tid] = ((const float2*)(x + (size_t)row0 * IN_C))[tid];
    // W = 8192 floats = 2048 float4: 8 per thread
    const float4* wsrc = (const float4*)W;
    float4*       wdst = (float4*)Ws;
#pragma unroll
    for (int j = 0; j < 8; ++j) wdst[tid + 256 * j] = wsrc[tid + 256 * j];
    __syncthreads();

    const int sub = tid >> 6;     // which of the 4 rows (== wave id)
    const int h   = tid & 63;
    const float* xr = xs + sub * IN_C;
    float acc = 0.f;
#pragma unroll
    for (int k = 0; k < IN_C; ++k) acc += xr[k] * Ws[k * HID + h];
    xlin[(size_t)(row0 + sub) * HID + h] = acc;
}

// ---------------------------------------------------------------- degrees + graph counts
__global__ void k_degcnt(const int* __restrict__ col, const int* __restrict__ batch,
                         int* __restrict__ deg, int* __restrict__ cnts) {
    int i = blockIdx.x * blockDim.x + threadIdx.x;
    if (i < N_EDGES) {
        atomicAdd(&deg[col[i]], 1);
    } else {
        int j = i - N_EDGES;
        if (j < N_NODES) atomicAdd(&cnts[batch[j]], 1);
    }
}

// ---------------------------------------------------------------- dinv + self-loop h init
__global__ void k_self(const int* __restrict__ deg, const float* __restrict__ xlin,
                       float* __restrict__ dinv, float* __restrict__ h) {
    int i    = blockIdx.x * blockDim.x + threadIdx.x;   // over N*HID
    int node = i >> 6;
    int hh   = i & 63;
    float dv = rsqrtf((float)deg[node]);                // deg >= 1 always
    if (hh == 0) dinv[node] = dv;
    h[i] = xlin[i] * (dv * dv);
}

// ---------------------------------------------------------------- edge scatter (wave per edge)
__global__ void k_edges(const int* __restrict__ row, const int* __restrict__ col,
                        const float* __restrict__ dinv, const float* __restrict__ xlin,
                        float* __restrict__ h) {
    int gid = blockIdx.x * blockDim.x + threadIdx.x;
    int e   = gid >> 6;
    int hh  = gid & 63;
    int r = row[e];
    int c = col[e];
    float norm = dinv[r] * dinv[c];
    atomicAdd(&h[(size_t)c * HID + hh], xlin[(size_t)r * HID + hh] * norm);
}

// ---------------------------------------------------------------- relu + mean-pool sums
// batch is sorted: each thread walks 16 consecutive nodes, flushing one atomic
// per batch-id change instead of one per node.
__global__ void k_pool(const float* __restrict__ h, const float* __restrict__ bias,
                       const int* __restrict__ batch, float* __restrict__ pooled) {
    const int NPT  = 16;
    const int hh   = threadIdx.x & 63;
    const int grp  = threadIdx.x >> 6;
    const int node0 = (blockIdx.x * 4 + grp) * NPT;
    float bsv = bias[hh];
    float acc = 0.f;
    int   cur = -1;
    for (int t = 0; t < NPT; ++t) {
        int node = node0 + t;
        if (node >= N_NODES) break;
        int   bg = batch[node];
        float v  = fmaxf(h[(size_t)node * HID + hh] + bsv, 0.f);
        if (bg != cur) {
            if (cur >= 0) atomicAdd(&pooled[cur * HID + hh], acc);
            cur = bg;
            acc = v;
        } else {
            acc += v;
        }
    }
    if (cur >= 0) atomicAdd(&pooled[cur * HID + hh], acc);
}

// ---------------------------------------------------------------- pooled/cnt @ Wfc + bfc
__global__ void k_out(const float* __restrict__ pooled, const int* __restrict__ cnts,
                      const float* __restrict__ Wfc, const float* __restrict__ bfc,
                      float* __restrict__ out) {
    int idx = blockIdx.x * blockDim.x + threadIdx.x;    // 2048 = 256*8
    int g = idx >> 3;
    int o = idx & 7;
    float inv = 1.f / fmaxf((float)cnts[g], 1.f);
    float acc = 0.f;
#pragma unroll
    for (int k = 0; k < HID; ++k) acc += pooled[g * HID + k] * Wfc[k * OUT_C + o];
    out[idx] = acc * inv + bfc[o];
}

// ---------------------------------------------------------------- launch
extern "C" void kernel_launch(void* const* d_in, const int* in_sizes, int n_in,
                              void* d_out, int out_size, void* d_ws, size_t ws_size,
                              hipStream_t stream) {
    const float* x     = (const float*)d_in[0];
    const int*   eidx  = (const int*)d_in[1];      // [2, E] flat
    const int*   batch = (const int*)d_in[2];
    const float* W     = (const float*)d_in[3];
    const float* b     = (const float*)d_in[4];
    const float* Wfc   = (const float*)d_in[5];
    const float* bfc   = (const float*)d_in[6];
    float*       out   = (float*)d_out;

    const int* row = eidx;            // src
    const int* col = eidx + N_EDGES;  // dst

    float* xlin   = (float*)d_ws;                       // N*HID
    float* h      = xlin + (size_t)N_NODES * HID;       // N*HID
    float* dinv   = h + (size_t)N_NODES * HID;          // N
    float* pooled = dinv + N_NODES;                     // NUM_G*HID
    int*   deg    = (int*)(pooled + NUM_G * HID);       // N
    int*   cnts   = deg + N_NODES;                      // NUM_G

    k_init<<<(N_NODES + 255) / 256, 256, 0, stream>>>(deg, pooled, cnts);
    k_lin<<<N_NODES / 4, 256, 0, stream>>>(x, W, xlin);
    k_degcnt<<<(N_EDGES + N_NODES + 255) / 256, 256, 0, stream>>>(col, batch, deg, cnts);
    k_self<<<(N_NODES * HID) / 256, 256, 0, stream>>>(deg, xlin, dinv, h);
    k_edges<<<(N_EDGES * HID) / 256, 256, 0, stream>>>(row, col, dinv, xlin, h);
    k_pool<<<(N_NODES + 63) / 64, 256, 0, stream>>>(h, b, batch, pooled);
    k_out<<<8, 256, 0, stream>>>(pooled, cnts, Wfc, bfc, out);
}

// Round 2
// 283.791 us; speedup vs baseline: 1.2054x; 1.2054x over previous
//
#include <hip/hip_runtime.h>

#define N_NODES 50000
#define N_EDGES 800000
#define IN_C    128
#define HID     64
#define NUM_G   256
#define OUT_C   8
#define NB_SCAN 196   // ceil(N_NODES/256)

// ---------------------------------------------------------------- init (zero ws state)
__global__ void k_init(int* __restrict__ hist, float* __restrict__ pooled,
                       int* __restrict__ cnts) {
    int i = blockIdx.x * blockDim.x + threadIdx.x;
    if (i < N_NODES) hist[i] = 0;
    if (i < NUM_G * HID) pooled[i] = 0.f;
    if (i < NUM_G) cnts[i] = 0;
}

// ---------------------------------------------------------------- x @ W  (k-chunk register GEMM)
// block = 256 threads: h = tid&63 (output col), q = tid>>6 (k-chunk of 32).
// Block computes 64 rows. W chunk lives in 32 regs/thread; x tile in LDS,
// read as float4 broadcasts (all lanes same addr -> conflict-free).
__global__ __launch_bounds__(256) void k_lin(const float* __restrict__ x,
                                             const float* __restrict__ W,
                                             float* __restrict__ xlin) {
    __shared__ float smem[64 * IN_C];   // 32 KiB: x tile, reused for reduction
    const int tid = threadIdx.x;
    const int h   = tid & 63;
    const int q   = tid >> 6;
    const size_t row0 = (size_t)blockIdx.x * 64;

    // stage x tile: 2048 float4, 8 per thread (guard tail block)
    {
        const float4* src = (const float4*)(x + row0 * IN_C);
        float4*       dst = (float4*)smem;
#pragma unroll
        for (int j = 0; j < 8; ++j) {
            int idx4 = tid + 256 * j;
            float4 v = make_float4(0.f, 0.f, 0.f, 0.f);
            if (row0 + (size_t)(idx4 >> 5) < N_NODES) v = src[idx4];
            dst[idx4] = v;
        }
    }
    // W chunk -> registers (coalesced per j: lanes h consecutive)
    float Wreg[32];
#pragma unroll
    for (int j = 0; j < 32; ++j) Wreg[j] = W[(q * 32 + j) * HID + h];
    __syncthreads();

    float p[64];
#pragma unroll
    for (int r = 0; r < 64; ++r) {
        const float* xr = smem + r * IN_C + q * 32;
        float acc = 0.f;
#pragma unroll
        for (int j = 0; j < 32; ++j) acc = fmaf(xr[j], Wreg[j], acc);
        p[r] = acc;
    }

    // reduce 4 k-chunk partials per (row, h); two 32-row passes through smem
#pragma unroll
    for (int half = 0; half < 2; ++half) {
        __syncthreads();
#pragma unroll
        for (int r = 0; r < 32; ++r)
            smem[r * 256 + q * 64 + h] = p[half * 32 + r];
        __syncthreads();
#pragma unroll
        for (int rr = 0; rr < 8; ++rr) {
            int rloc = q * 8 + rr;
            float v = smem[rloc * 256 + h] + smem[rloc * 256 + 64 + h]
                    + smem[rloc * 256 + 128 + h] + smem[rloc * 256 + 192 + h];
            size_t row = row0 + half * 32 + rloc;
            if (row < N_NODES) xlin[row * HID + h] = v;
        }
    }
}

// ---------------------------------------------------------------- in-degree histogram + graph counts
__global__ void k_hist(const int* __restrict__ col, const int* __restrict__ batch,
                       int* __restrict__ hist, int* __restrict__ cnts) {
    int i = blockIdx.x * blockDim.x + threadIdx.x;
    if (i < N_EDGES) {
        atomicAdd(&hist[col[i]], 1);
    } else {
        int j = i - N_EDGES;
        if (j < N_NODES) atomicAdd(&cnts[batch[j]], 1);
    }
}

// ---------------------------------------------------------------- scan (3 kernels)
__global__ void k_scanA(const int* __restrict__ hist, int* __restrict__ tmp,
                        int* __restrict__ blkSum) {
    __shared__ int s[256];
    int tid = threadIdx.x;
    int i = blockIdx.x * 256 + tid;
    int v = (i < N_NODES) ? hist[i] : 0;
    s[tid] = v;
    __syncthreads();
    int acc = v;
#pragma unroll
    for (int off = 1; off < 256; off <<= 1) {
        int t = (tid >= off) ? s[tid - off] : 0;
        __syncthreads();
        acc += t;
        s[tid] = acc;
        __syncthreads();
    }
    if (i < N_NODES) tmp[i] = acc - v;      // exclusive within block
    if (tid == 255) blkSum[blockIdx.x] = acc;
}

__global__ void k_scanB(int* __restrict__ blkSum) {   // in-place exclusive, 1 block
    __shared__ int s[256];
    int tid = threadIdx.x;
    int v = (tid < NB_SCAN) ? blkSum[tid] : 0;
    s[tid] = v;
    __syncthreads();
    int acc = v;
#pragma unroll
    for (int off = 1; off < 256; off <<= 1) {
        int t = (tid >= off) ? s[tid - off] : 0;
        __syncthreads();
        acc += t;
        s[tid] = acc;
        __syncthreads();
    }
    blkSum[tid] = acc - v;
}

__global__ void k_scanC(const int* __restrict__ tmp, const int* __restrict__ blkOff,
                        const int* __restrict__ hist, int* __restrict__ node_start,
                        int* __restrict__ cursor, float* __restrict__ dinv) {
    int i = blockIdx.x * 256 + threadIdx.x;
    if (i < N_NODES) {
        int st = tmp[i] + blkOff[blockIdx.x];
        node_start[i] = st;
        cursor[i]     = st;
        dinv[i] = rsqrtf((float)(hist[i] + 1));        // +1 self-loop
        if (i == N_NODES - 1) node_start[N_NODES] = N_EDGES;
    }
}

// ---------------------------------------------------------------- scatter edges to CSR (dst-sorted)
__global__ void k_scatter(const int* __restrict__ row, const int* __restrict__ col,
                          const float* __restrict__ dinv, int* __restrict__ cursor,
                          int2* __restrict__ ed) {
    int e = blockIdx.x * blockDim.x + threadIdx.x;
    if (e >= N_EDGES) return;
    int s = row[e];
    int d = col[e];
    int pos = atomicAdd(&cursor[d], 1);
    float nrm = dinv[s] * dinv[d];
    ed[pos] = make_int2(s, __float_as_int(nrm));
}

// ---------------------------------------------------------------- pull-mode aggregation (no atomics)
// wave per destination node: 64 lanes = 64 hid dims.
__global__ __launch_bounds__(256) void k_gather(const int2* __restrict__ ed,
                                                const int* __restrict__ node_start,
                                                const float* __restrict__ dinv,
                                                const float* __restrict__ xlin,
                                                float* __restrict__ h) {
    const int lane = threadIdx.x & 63;
    const int node = blockIdx.x * 4 + (threadIdx.x >> 6);
    if (node >= N_NODES) return;
    const int n0 = node_start[node];
    const int n1 = node_start[node + 1];
    const float dvd = dinv[node];
    float acc = xlin[(size_t)node * HID + lane] * (dvd * dvd);   // self-loop

    int t = n0;
    for (; t + 4 <= n1; t += 4) {
        int2 e0 = ed[t], e1 = ed[t + 1], e2 = ed[t + 2], e3 = ed[t + 3];
        int s0 = __builtin_amdgcn_readfirstlane(e0.x);
        int s1 = __builtin_amdgcn_readfirstlane(e1.x);
        int s2 = __builtin_amdgcn_readfirstlane(e2.x);
        int s3 = __builtin_amdgcn_readfirstlane(e3.x);
        float w0 = __int_as_float(__builtin_amdgcn_readfirstlane(e0.y));
        float w1 = __int_as_float(__builtin_amdgcn_readfirstlane(e1.y));
        float w2 = __int_as_float(__builtin_amdgcn_readfirstlane(e2.y));
        float w3 = __int_as_float(__builtin_amdgcn_readfirstlane(e3.y));
        float v0 = xlin[(size_t)s0 * HID + lane];
        float v1 = xlin[(size_t)s1 * HID + lane];
        float v2 = xlin[(size_t)s2 * HID + lane];
        float v3 = xlin[(size_t)s3 * HID + lane];
        acc = fmaf(v0, w0, acc);
        acc = fmaf(v1, w1, acc);
        acc = fmaf(v2, w2, acc);
        acc = fmaf(v3, w3, acc);
    }
    for (; t < n1; ++t) {
        int2 e = ed[t];
        int sfl = __builtin_amdgcn_readfirstlane(e.x);
        float wfl = __int_as_float(__builtin_amdgcn_readfirstlane(e.y));
        acc = fmaf(xlin[(size_t)sfl * HID + lane], wfl, acc);
    }
    h[(size_t)node * HID + lane] = acc;
}

// ---------------------------------------------------------------- relu + mean-pool sums
__global__ void k_pool(const float* __restrict__ h, const float* __restrict__ bias,
                       const int* __restrict__ batch, float* __restrict__ pooled) {
    const int NPT   = 16;
    const int hh    = threadIdx.x & 63;
    const int grp   = threadIdx.x >> 6;
    const int node0 = (blockIdx.x * 4 + grp) * NPT;
    float bsv = bias[hh];
    float acc = 0.f;
    int   cur = -1;
    for (int t = 0; t < NPT; ++t) {
        int node = node0 + t;
        if (node >= N_NODES) break;
        int   bg = batch[node];
        float v  = fmaxf(h[(size_t)node * HID + hh] + bsv, 0.f);
        if (bg != cur) {
            if (cur >= 0) atomicAdd(&pooled[cur * HID + hh], acc);
            cur = bg;
            acc = v;
        } else {
            acc += v;
        }
    }
    if (cur >= 0) atomicAdd(&pooled[cur * HID + hh], acc);
}

// ---------------------------------------------------------------- pooled/cnt @ Wfc + bfc
__global__ void k_out(const float* __restrict__ pooled, const int* __restrict__ cnts,
                      const float* __restrict__ Wfc, const float* __restrict__ bfc,
                      float* __restrict__ out) {
    int idx = blockIdx.x * blockDim.x + threadIdx.x;    // 2048 = 256*8
    int g = idx >> 3;
    int o = idx & 7;
    float inv = 1.f / fmaxf((float)cnts[g], 1.f);
    float acc = 0.f;
#pragma unroll
    for (int k = 0; k < HID; ++k) acc += pooled[g * HID + k] * Wfc[k * OUT_C + o];
    out[idx] = acc * inv + bfc[o];
}

// ---------------------------------------------------------------- launch
extern "C" void kernel_launch(void* const* d_in, const int* in_sizes, int n_in,
                              void* d_out, int out_size, void* d_ws, size_t ws_size,
                              hipStream_t stream) {
    const float* x     = (const float*)d_in[0];
    const int*   eidx  = (const int*)d_in[1];      // [2, E] flat
    const int*   batch = (const int*)d_in[2];
    const float* W     = (const float*)d_in[3];
    const float* b     = (const float*)d_in[4];
    const float* Wfc   = (const float*)d_in[5];
    const float* bfc   = (const float*)d_in[6];
    float*       out   = (float*)d_out;

    const int* row = eidx;            // src
    const int* col = eidx + N_EDGES;  // dst

    // ---- workspace layout (all 16B-friendly) ----
    float* xlin   = (float*)d_ws;                         // N*HID
    float* h      = xlin + (size_t)N_NODES * HID;         // N*HID
    float* dinv   = h + (size_t)N_NODES * HID;            // N
    float* pooled = dinv + N_NODES;                       // NUM_G*HID
    int2*  ed     = (int2*)(pooled + NUM_G * HID);        // E (src, norm)
    int*   hist   = (int*)(ed + N_EDGES);                 // N
    int*   nstart = hist + N_NODES;                       // N+1
    int*   cursor = nstart + N_NODES + 1;                 // N
    int*   tmp    = cursor + N_NODES;                     // N
    int*   blkSum = tmp + N_NODES;                        // 256
    int*   cnts   = blkSum + 256;                         // NUM_G

    k_init   <<<NB_SCAN, 256, 0, stream>>>(hist, pooled, cnts);
    k_lin    <<<(N_NODES + 63) / 64, 256, 0, stream>>>(x, W, xlin);
    k_hist   <<<(N_EDGES + N_NODES + 255) / 256, 256, 0, stream>>>(col, batch, hist, cnts);
    k_scanA  <<<NB_SCAN, 256, 0, stream>>>(hist, tmp, blkSum);
    k_scanB  <<<1, 256, 0, stream>>>(blkSum);
    k_scanC  <<<NB_SCAN, 256, 0, stream>>>(tmp, blkSum, hist, nstart, cursor, dinv);
    k_scatter<<<(N_EDGES + 255) / 256, 256, 0, stream>>>(row, col, dinv, cursor, ed);
    k_gather <<<(N_NODES + 3) / 4, 256, 0, stream>>>(ed, nstart, dinv, xlin, h);
    k_pool   <<<(N_NODES + 63) / 64, 256, 0, stream>>>(h, b, batch, pooled);
    k_out    <<<8, 256, 0, stream>>>(pooled, cnts, Wfc, bfc, out);
}

// Round 3
// 175.212 us; speedup vs baseline: 1.9524x; 1.6197x over previous
//
#include <hip/hip_runtime.h>
#include <stdint.h>

#define N_NODES 50000
#define N_EDGES 800000
#define IN_C    128
#define HID     64
#define NUM_G   256
#define OUT_C   8

#define NBH   64                 // histogram/scatter blocks
#define ES    (N_EDGES / NBH)    // 12500 edges per block
#define NBIN  50048              // padded bin count (even)
#define NPK   (NBIN / 2)         // 25024 packed u16-pair ints
#define NB_SCAN ((NBIN + 255) / 256)   // 196

__device__ __forceinline__ void gload_lds16(const void* g, void* l) {
    __builtin_amdgcn_global_load_lds(
        (const __attribute__((address_space(1))) unsigned int*)g,
        (__attribute__((address_space(3))) unsigned int*)l, 16, 0, 0);
}

// ---------------------------------------------------------------- init (pooled only)
__global__ void k_init(float* __restrict__ pooled) {
    int i = blockIdx.x * blockDim.x + threadIdx.x;
    if (i < NUM_G * HID) pooled[i] = 0.f;
}

// ---------------------------------------------------------------- per-block LDS histogram (u16-packed)
__global__ __launch_bounds__(256) void k_histB(const int* __restrict__ col,
                                               int* __restrict__ part) {
    __shared__ int lh[NPK];          // 100 KB
    const int tid = threadIdx.x;
    for (int i = tid; i < NPK; i += 256) lh[i] = 0;
    __syncthreads();
    const int base = blockIdx.x * ES;
    for (int j = tid; j < ES; j += 256) {
        int d = col[base + j];
        atomicAdd(&lh[d >> 1], 1 << ((d & 1) * 16));
    }
    __syncthreads();
    int* dst = part + blockIdx.x * NPK;
    for (int i = tid; i < NPK; i += 256) dst[i] = lh[i];
}

// ---------------------------------------------------------------- reduce partials -> deg; part becomes blockbase; dinv fused
__global__ void k_red(int* __restrict__ part, int* __restrict__ hist,
                      float* __restrict__ dinv) {
    int t = blockIdx.x * 256 + threadIdx.x;
    if (t >= NPK) return;
    int s0 = 0, s1 = 0;
    int idx = t;
    for (int b = 0; b < NBH; ++b, idx += NPK) {
        int v = part[idx];
        part[idx] = s0 | (s1 << 16);          // exclusive per-block offset
        s0 += v & 0xffff;
        s1 += (v >> 16) & 0xffff;
    }
    ((int2*)hist)[t]   = make_int2(s0, s1);
    ((float2*)dinv)[t] = make_float2(rsqrtf((float)(s0 + 1)),
                                     rsqrtf((float)(s1 + 1)));
}

// ---------------------------------------------------------------- scan (3 kernels) over NBIN
__global__ void k_scanA(const int* __restrict__ hist, int* __restrict__ tmp,
                        int* __restrict__ blkSum) {
    __shared__ int s[256];
    int tid = threadIdx.x;
    int i = blockIdx.x * 256 + tid;
    int v = (i < NBIN) ? hist[i] : 0;
    s[tid] = v;
    __syncthreads();
    int acc = v;
#pragma unroll
    for (int off = 1; off < 256; off <<= 1) {
        int t = (tid >= off) ? s[tid - off] : 0;
        __syncthreads();
        acc += t;
        s[tid] = acc;
        __syncthreads();
    }
    if (i < NBIN) tmp[i] = acc - v;
    if (tid == 255) blkSum[blockIdx.x] = acc;
}

__global__ void k_scanB(int* __restrict__ blkSum) {
    __shared__ int s[256];
    int tid = threadIdx.x;
    int v = (tid < NB_SCAN) ? blkSum[tid] : 0;
    s[tid] = v;
    __syncthreads();
    int acc = v;
#pragma unroll
    for (int off = 1; off < 256; off <<= 1) {
        int t = (tid >= off) ? s[tid - off] : 0;
        __syncthreads();
        acc += t;
        s[tid] = acc;
        __syncthreads();
    }
    blkSum[tid] = acc - v;
}

__global__ void k_scanC(const int* __restrict__ tmp, const int* __restrict__ blkOff,
                        int* __restrict__ nstart) {
    int i = blockIdx.x * 256 + threadIdx.x;
    if (i < N_NODES) {
        nstart[i] = tmp[i] + blkOff[blockIdx.x];
        if (i == 0) nstart[N_NODES] = N_EDGES;
    }
}

// ---------------------------------------------------------------- scatter via LDS cursors (no global atomics)
__global__ __launch_bounds__(256) void k_scat2(const int* __restrict__ row,
                                               const int* __restrict__ col,
                                               const int* __restrict__ part,
                                               const int* __restrict__ nstart,
                                               int* __restrict__ ed) {
    __shared__ int lc[NPK];          // 100 KB, full-int cursors per pass
    const int tid = threadIdx.x;
    const int b = blockIdx.x;
    const int base = b * ES;
#pragma unroll 1
    for (int pass = 0; pass < 2; ++pass) {
        const int bin0 = pass * NPK;
        __syncthreads();
        for (int i = tid; i < NPK; i += 256) {
            int bin = bin0 + i;
            int bb = part[b * NPK + (bin >> 1)];
            int off = (bin & 1) ? ((bb >> 16) & 0xffff) : (bb & 0xffff);
            lc[i] = nstart[bin] + off;       // nstart padded to NBIN+1
        }
        __syncthreads();
        for (int j = tid; j < ES; j += 256) {
            int e = base + j;
            int d = col[e];
            if (d >= bin0 && d < bin0 + NPK) {
                int pos = atomicAdd(&lc[d - bin0], 1);
                ed[pos] = row[e];
            }
        }
    }
}

// ---------------------------------------------------------------- y = (x @ W) * dinv[row]  (64x64 tile, 4x4/thread)
__global__ __launch_bounds__(256) void k_lin(const float* __restrict__ x,
                                             const float* __restrict__ W,
                                             const float* __restrict__ dinv,
                                             float* __restrict__ y) {
    __shared__ float xs[64 * IN_C];   // 32 KB
    __shared__ float Ws[IN_C * HID];  // 32 KB
    const int tid = threadIdx.x;
    const size_t row0 = (size_t)blockIdx.x * 64;
    const int ln = tid & 63, wv = tid >> 6;

    {   // stage W via global_load_lds (32 chunks of 1 KB)
        const char* wsrc = (const char*)W;
#pragma unroll
        for (int it = 0; it < 8; ++it) {
            int c = wv * 8 + it;
            gload_lds16(wsrc + c * 1024 + ln * 16, (char*)Ws + c * 1024);
        }
    }
    if (row0 + 64 <= N_NODES) {
        const char* gsrc = (const char*)(x + row0 * IN_C);
#pragma unroll
        for (int it = 0; it < 8; ++it) {
            int c = wv * 8 + it;
            gload_lds16(gsrc + c * 1024 + ln * 16, (char*)xs + c * 1024);
        }
    } else {
        const float4* src = (const float4*)(x + row0 * IN_C);
        for (int i4 = tid; i4 < 2048; i4 += 256) {
            int r = i4 >> 5;
            float4 v = make_float4(0.f, 0.f, 0.f, 0.f);
            if (row0 + r < N_NODES) v = src[i4];
            ((float4*)xs)[i4] = v;
        }
    }
    __syncthreads();

    const int ty = tid >> 4, tx = tid & 15;
    const int r0 = ty * 4, c0 = tx * 4;
    float acc[4][4] = {};

#define AC(ai, kk) ((kk)==0 ? av##ai.x : (kk)==1 ? av##ai.y : (kk)==2 ? av##ai.z : av##ai.w)
#define ROWF(ai, kk, bv) \
    acc[ai][0] = fmaf(AC(ai,kk), bv.x, acc[ai][0]); \
    acc[ai][1] = fmaf(AC(ai,kk), bv.y, acc[ai][1]); \
    acc[ai][2] = fmaf(AC(ai,kk), bv.z, acc[ai][2]); \
    acc[ai][3] = fmaf(AC(ai,kk), bv.w, acc[ai][3]);
#define K4(kk, bv) ROWF(0,kk,bv) ROWF(1,kk,bv) ROWF(2,kk,bv) ROWF(3,kk,bv)

    for (int k = 0; k < IN_C; k += 4) {
        float4 av0 = *(const float4*)&xs[(r0+0)*IN_C + k];
        float4 av1 = *(const float4*)&xs[(r0+1)*IN_C + k];
        float4 av2 = *(const float4*)&xs[(r0+2)*IN_C + k];
        float4 av3 = *(const float4*)&xs[(r0+3)*IN_C + k];
        float4 bv0 = *(const float4*)&Ws[(k+0)*HID + c0];
        float4 bv1 = *(const float4*)&Ws[(k+1)*HID + c0];
        float4 bv2 = *(const float4*)&Ws[(k+2)*HID + c0];
        float4 bv3 = *(const float4*)&Ws[(k+3)*HID + c0];
        K4(0, bv0) K4(1, bv1) K4(2, bv2) K4(3, bv3)
    }
#undef K4
#undef ROWF
#undef AC

#pragma unroll
    for (int i = 0; i < 4; ++i) {
        size_t r = row0 + r0 + i;
        if (r < N_NODES) {
            float dv = dinv[r];
            float4 o = make_float4(acc[i][0]*dv, acc[i][1]*dv,
                                   acc[i][2]*dv, acc[i][3]*dv);
            *(float4*)&y[r * HID + c0] = o;
        }
    }
}

// ---------------------------------------------------------------- pull aggregation: h[d] = dinv[d]*(y[d]+sum y[src])
__global__ __launch_bounds__(256) void k_gather(const int* __restrict__ ed,
                                                const int* __restrict__ nstart,
                                                const float* __restrict__ dinv,
                                                const float* __restrict__ y,
                                                float* __restrict__ h) {
    const int lane = threadIdx.x & 63;
    const int node = blockIdx.x * 4 + (threadIdx.x >> 6);
    if (node >= N_NODES) return;
    const int n0 = nstart[node], n1 = nstart[node + 1];
    float acc = y[(size_t)node * HID + lane];   // self-loop term
    int t = n0;
    for (; t + 4 <= n1; t += 4) {
        int s0 = __builtin_amdgcn_readfirstlane(ed[t]);
        int s1 = __builtin_amdgcn_readfirstlane(ed[t+1]);
        int s2 = __builtin_amdgcn_readfirstlane(ed[t+2]);
        int s3 = __builtin_amdgcn_readfirstlane(ed[t+3]);
        float v0 = y[(size_t)s0 * HID + lane];
        float v1 = y[(size_t)s1 * HID + lane];
        float v2 = y[(size_t)s2 * HID + lane];
        float v3 = y[(size_t)s3 * HID + lane];
        acc += (v0 + v1) + (v2 + v3);
    }
    for (; t < n1; ++t) {
        int s = __builtin_amdgcn_readfirstlane(ed[t]);
        acc += y[(size_t)s * HID + lane];
    }
    h[(size_t)node * HID + lane] = acc * dinv[node];
}

// ---------------------------------------------------------------- relu + mean-pool sums (batch sorted)
__global__ void k_pool(const float* __restrict__ h, const float* __restrict__ bias,
                       const int* __restrict__ batch, float* __restrict__ pooled) {
    const int NPT   = 16;
    const int hh    = threadIdx.x & 63;
    const int grp   = threadIdx.x >> 6;
    const int node0 = (blockIdx.x * 4 + grp) * NPT;
    float bsv = bias[hh];
    float acc = 0.f;
    int   cur = -1;
    for (int t = 0; t < NPT; ++t) {
        int node = node0 + t;
        if (node >= N_NODES) break;
        int   bg = batch[node];
        float v  = fmaxf(h[(size_t)node * HID + hh] + bsv, 0.f);
        if (bg != cur) {
            if (cur >= 0) atomicAdd(&pooled[cur * HID + hh], acc);
            cur = bg;
            acc = v;
        } else {
            acc += v;
        }
    }
    if (cur >= 0) atomicAdd(&pooled[cur * HID + hh], acc);
}

// ---------------------------------------------------------------- graph boundaries by binary search (batch sorted)
__global__ void k_cnts(const int* __restrict__ batch, int* __restrict__ gstart) {
    int g = blockIdx.x * blockDim.x + threadIdx.x;
    if (g > NUM_G) return;
    int lo = 0, hi = N_NODES;
    while (lo < hi) {
        int mid = (lo + hi) >> 1;
        if (batch[mid] < g) lo = mid + 1; else hi = mid;
    }
    gstart[g] = lo;
}

// ---------------------------------------------------------------- pooled/cnt @ Wfc + bfc
__global__ void k_out(const float* __restrict__ pooled, const int* __restrict__ gstart,
                      const float* __restrict__ Wfc, const float* __restrict__ bfc,
                      float* __restrict__ out) {
    int idx = blockIdx.x * blockDim.x + threadIdx.x;    // 2048 = 256*8
    int g = idx >> 3;
    int o = idx & 7;
    float inv = 1.f / fmaxf((float)(gstart[g + 1] - gstart[g]), 1.f);
    float acc = 0.f;
#pragma unroll
    for (int k = 0; k < HID; ++k) acc += pooled[g * HID + k] * Wfc[k * OUT_C + o];
    out[idx] = acc * inv + bfc[o];
}

// ---------------------------------------------------------------- launch
extern "C" void kernel_launch(void* const* d_in, const int* in_sizes, int n_in,
                              void* d_out, int out_size, void* d_ws, size_t ws_size,
                              hipStream_t stream) {
    const float* x     = (const float*)d_in[0];
    const int*   eidx  = (const int*)d_in[1];      // [2, E] flat
    const int*   batch = (const int*)d_in[2];
    const float* W     = (const float*)d_in[3];
    const float* b     = (const float*)d_in[4];
    const float* Wfc   = (const float*)d_in[5];
    const float* bfc   = (const float*)d_in[6];
    float*       out   = (float*)d_out;

    const int* row = eidx;            // src
    const int* col = eidx + N_EDGES;  // dst

    // ---- workspace layout ----
    float* y      = (float*)d_ws;                         // N*HID
    float* h      = y + (size_t)N_NODES * HID;            // N*HID
    int*   part   = (int*)h;                              // NBH*NPK ints, aliases h (dead before gather)
    float* dinv   = h + (size_t)N_NODES * HID;            // NBIN
    float* pooled = dinv + NBIN;                          // NUM_G*HID
    int*   hist   = (int*)(pooled + NUM_G * HID);         // NBIN
    int*   nstart = hist + NBIN;                          // NBIN+1 (padded)
    int*   tmp    = nstart + NBIN + 4;                    // NBIN
    int*   blkSum = tmp + NBIN;                           // 256
    int*   gstart = blkSum + 256;                         // 257
    int*   ed     = gstart + 260;                         // E

    k_init  <<<(NUM_G * HID + 255) / 256, 256, 0, stream>>>(pooled);
    k_histB <<<NBH, 256, 0, stream>>>(col, part);
    k_red   <<<(NPK + 255) / 256, 256, 0, stream>>>(part, hist, dinv);
    k_scanA <<<NB_SCAN, 256, 0, stream>>>(hist, tmp, blkSum);
    k_scanB <<<1, 256, 0, stream>>>(blkSum);
    k_scanC <<<NB_SCAN, 256, 0, stream>>>(tmp, blkSum, nstart);
    k_scat2 <<<NBH, 256, 0, stream>>>(row, col, part, nstart, ed);
    k_lin   <<<(N_NODES + 63) / 64, 256, 0, stream>>>(x, W, dinv, y);
    k_gather<<<(N_NODES + 3) / 4, 256, 0, stream>>>(ed, nstart, dinv, y, h);
    k_pool  <<<(N_NODES + 63) / 64, 256, 0, stream>>>(h, b, batch, pooled);
    k_cnts  <<<2, 256, 0, stream>>>(batch, gstart);
    k_out   <<<8, 256, 0, stream>>>(pooled, gstart, Wfc, bfc, out);
}

// Round 4
// 142.740 us; speedup vs baseline: 2.3966x; 1.2275x over previous
//
#include <hip/hip_runtime.h>
#include <stdint.h>

#define N_NODES 50000
#define N_EDGES 800000
#define IN_C    128
#define HID     64
#define NUM_G   256
#define OUT_C   8

#define NBH   64                 // edge-ranges
#define ES    (N_EDGES / NBH)    // 12500 edges per range
#define NBIN  50048              // padded bin count (even)
#define NPK   (NBIN / 2)         // 25024 packed u16-pair ints
#define NB_SCAN ((NBIN + 255) / 256)   // 196

#define NQ_H   4                 // histogram bin-quarters
#define BINS_H (NBIN / NQ_H)     // 12512 bins per hist block
#define PK_H   (BINS_H / 2)      // 6256 packed ints (25 KB LDS)
#define NQ_S   8                 // scatter bin-eighths
#define BINS_S (NBIN / NQ_S)     // 6256 bins per scat block (25 KB LDS)

__device__ __forceinline__ void gload_lds16(const void* g, void* l) {
    __builtin_amdgcn_global_load_lds(
        (const __attribute__((address_space(1))) unsigned int*)g,
        (__attribute__((address_space(3))) unsigned int*)l, 16, 0, 0);
}

// ---------------------------------------------------------------- init pooled + graph boundaries
__global__ void k_initcnt(float* __restrict__ pooled, const int* __restrict__ batch,
                          int* __restrict__ gstart) {
    int i = blockIdx.x * blockDim.x + threadIdx.x;
    if (i < NUM_G * HID) pooled[i] = 0.f;
    if (i <= NUM_G) {
        int lo = 0, hi = N_NODES;
        while (lo < hi) {
            int mid = (lo + hi) >> 1;
            if (batch[mid] < i) lo = mid + 1; else hi = mid;
        }
        gstart[i] = lo;
    }
}

// ---------------------------------------------------------------- LDS histogram: 64 ranges x 4 bin-quarters
__global__ __launch_bounds__(256) void k_histB(const int* __restrict__ col,
                                               int* __restrict__ part) {
    __shared__ int lh[PK_H];                 // 25 KB
    const int tid = threadIdx.x;
    const int r = blockIdx.x >> 2;
    const int q = blockIdx.x & 3;
    const int q0 = q * BINS_H;
    for (int i = tid; i < PK_H; i += 256) lh[i] = 0;
    __syncthreads();
    const int base = r * ES;
    for (int j = tid; j < ES; j += 256) {
        int d = col[base + j];
        unsigned dd = (unsigned)(d - q0);
        if (dd < BINS_H) atomicAdd(&lh[dd >> 1], 1 << ((dd & 1) * 16));
    }
    __syncthreads();
    int* dst = part + r * NPK + q * PK_H;
    for (int i = tid; i < PK_H; i += 256) dst[i] = lh[i];
}

// ---------------------------------------------------------------- reduce partials -> deg; part becomes blockbase; dinv fused
__global__ void k_red(int* __restrict__ part, int* __restrict__ hist,
                      float* __restrict__ dinv) {
    int t = blockIdx.x * 256 + threadIdx.x;
    if (t >= NPK) return;
    int s0 = 0, s1 = 0;
    int idx = t;
#pragma unroll 4
    for (int b = 0; b < NBH; ++b, idx += NPK) {
        int v = part[idx];
        part[idx] = s0 | (s1 << 16);          // exclusive per-range offset
        s0 += v & 0xffff;
        s1 += (v >> 16) & 0xffff;
    }
    ((int2*)hist)[t]   = make_int2(s0, s1);
    ((float2*)dinv)[t] = make_float2(rsqrtf((float)(s0 + 1)),
                                     rsqrtf((float)(s1 + 1)));
}

// ---------------------------------------------------------------- scan (3 kernels) over NBIN
__global__ void k_scanA(const int* __restrict__ hist, int* __restrict__ tmp,
                        int* __restrict__ blkSum) {
    __shared__ int s[256];
    int tid = threadIdx.x;
    int i = blockIdx.x * 256 + tid;
    int v = (i < NBIN) ? hist[i] : 0;
    s[tid] = v;
    __syncthreads();
    int acc = v;
#pragma unroll
    for (int off = 1; off < 256; off <<= 1) {
        int t = (tid >= off) ? s[tid - off] : 0;
        __syncthreads();
        acc += t;
        s[tid] = acc;
        __syncthreads();
    }
    if (i < NBIN) tmp[i] = acc - v;
    if (tid == 255) blkSum[blockIdx.x] = acc;
}

__global__ void k_scanB(int* __restrict__ blkSum) {
    __shared__ int s[256];
    int tid = threadIdx.x;
    int v = (tid < NB_SCAN) ? blkSum[tid] : 0;
    s[tid] = v;
    __syncthreads();
    int acc = v;
#pragma unroll
    for (int off = 1; off < 256; off <<= 1) {
        int t = (tid >= off) ? s[tid - off] : 0;
        __syncthreads();
        acc += t;
        s[tid] = acc;
        __syncthreads();
    }
    blkSum[tid] = acc - v;
}

__global__ void k_scanC(const int* __restrict__ tmp, const int* __restrict__ blkOff,
                        int* __restrict__ nstart) {
    int i = blockIdx.x * 256 + threadIdx.x;
    if (i < NBIN) nstart[i] = tmp[i] + blkOff[blockIdx.x];
    // bins >= N_NODES have zero counts, so nstart there == N_EDGES;
    // gather reads nstart[node+1] up to index N_NODES — valid.
}

// ---------------------------------------------------------------- scatter: 64 ranges x 8 bin-eighths, LDS cursors
__global__ __launch_bounds__(256) void k_scat2(const int* __restrict__ row,
                                               const int* __restrict__ col,
                                               const int* __restrict__ part,
                                               const int* __restrict__ nstart,
                                               int* __restrict__ ed) {
    __shared__ int lc[BINS_S];               // 25 KB
    const int tid = threadIdx.x;
    const int r = blockIdx.x >> 3;
    const int q = blockIdx.x & 7;
    const int q0 = q * BINS_S;
    for (int i = tid; i < BINS_S; i += 256) {
        int bin = q0 + i;
        int bb = part[r * NPK + (bin >> 1)];
        int off = (i & 1) ? ((bb >> 16) & 0xffff) : (bb & 0xffff);
        lc[i] = nstart[bin] + off;
    }
    __syncthreads();
    const int base = r * ES;
    for (int j = tid; j < ES; j += 256) {
        int e = base + j;
        int d = col[e];
        unsigned dd = (unsigned)(d - q0);
        if (dd < BINS_S) {
            int pos = atomicAdd(&lc[dd], 1);
            ed[pos] = row[e];
        }
    }
}

// ---------------------------------------------------------------- y = (x @ W) * dinv[row]  (64x64 tile, 4x4/thread)
__global__ __launch_bounds__(256) void k_lin(const float* __restrict__ x,
                                             const float* __restrict__ W,
                                             const float* __restrict__ dinv,
                                             float* __restrict__ y) {
    __shared__ float xs[64 * IN_C];   // 32 KB
    __shared__ float Ws[IN_C * HID];  // 32 KB
    const int tid = threadIdx.x;
    const size_t row0 = (size_t)blockIdx.x * 64;
    const int ln = tid & 63, wv = tid >> 6;

    {   // stage W via global_load_lds (32 chunks of 1 KB)
        const char* wsrc = (const char*)W;
#pragma unroll
        for (int it = 0; it < 8; ++it) {
            int c = wv * 8 + it;
            gload_lds16(wsrc + c * 1024 + ln * 16, (char*)Ws + c * 1024);
        }
    }
    if (row0 + 64 <= N_NODES) {
        const char* gsrc = (const char*)(x + row0 * IN_C);
#pragma unroll
        for (int it = 0; it < 8; ++it) {
            int c = wv * 8 + it;
            gload_lds16(gsrc + c * 1024 + ln * 16, (char*)xs + c * 1024);
        }
    } else {
        const float4* src = (const float4*)(x + row0 * IN_C);
        for (int i4 = tid; i4 < 2048; i4 += 256) {
            int r = i4 >> 5;
            float4 v = make_float4(0.f, 0.f, 0.f, 0.f);
            if (row0 + r < N_NODES) v = src[i4];
            ((float4*)xs)[i4] = v;
        }
    }
    __syncthreads();

    const int ty = tid >> 4, tx = tid & 15;
    const int r0 = ty * 4, c0 = tx * 4;
    float acc[4][4] = {};

#define AC(ai, kk) ((kk)==0 ? av##ai.x : (kk)==1 ? av##ai.y : (kk)==2 ? av##ai.z : av##ai.w)
#define ROWF(ai, kk, bv) \
    acc[ai][0] = fmaf(AC(ai,kk), bv.x, acc[ai][0]); \
    acc[ai][1] = fmaf(AC(ai,kk), bv.y, acc[ai][1]); \
    acc[ai][2] = fmaf(AC(ai,kk), bv.z, acc[ai][2]); \
    acc[ai][3] = fmaf(AC(ai,kk), bv.w, acc[ai][3]);
#define K4(kk, bv) ROWF(0,kk,bv) ROWF(1,kk,bv) ROWF(2,kk,bv) ROWF(3,kk,bv)

    for (int k = 0; k < IN_C; k += 4) {
        float4 av0 = *(const float4*)&xs[(r0+0)*IN_C + k];
        float4 av1 = *(const float4*)&xs[(r0+1)*IN_C + k];
        float4 av2 = *(const float4*)&xs[(r0+2)*IN_C + k];
        float4 av3 = *(const float4*)&xs[(r0+3)*IN_C + k];
        float4 bv0 = *(const float4*)&Ws[(k+0)*HID + c0];
        float4 bv1 = *(const float4*)&Ws[(k+1)*HID + c0];
        float4 bv2 = *(const float4*)&Ws[(k+2)*HID + c0];
        float4 bv3 = *(const float4*)&Ws[(k+3)*HID + c0];
        K4(0, bv0) K4(1, bv1) K4(2, bv2) K4(3, bv3)
    }
#undef K4
#undef ROWF
#undef AC

#pragma unroll
    for (int i = 0; i < 4; ++i) {
        size_t r = row0 + r0 + i;
        if (r < N_NODES) {
            float dv = dinv[r];
            float4 o = make_float4(acc[i][0]*dv, acc[i][1]*dv,
                                   acc[i][2]*dv, acc[i][3]*dv);
            *(float4*)&y[r * HID + c0] = o;
        }
    }
}

// ---------------------------------------------------------------- pull aggregation: h[d] = dinv[d]*(y[d]+sum y[src])
__global__ __launch_bounds__(256) void k_gather(const int* __restrict__ ed,
                                                const int* __restrict__ nstart,
                                                const float* __restrict__ dinv,
                                                const float* __restrict__ y,
                                                float* __restrict__ h) {
    const int lane = threadIdx.x & 63;
    const int node = blockIdx.x * 4 + (threadIdx.x >> 6);
    if (node >= N_NODES) return;
    const int n0 = nstart[node], n1 = nstart[node + 1];
    float acc = y[(size_t)node * HID + lane];   // self-loop term
    int t = n0;
    for (; t + 4 <= n1; t += 4) {
        int s0 = __builtin_amdgcn_readfirstlane(ed[t]);
        int s1 = __builtin_amdgcn_readfirstlane(ed[t+1]);
        int s2 = __builtin_amdgcn_readfirstlane(ed[t+2]);
        int s3 = __builtin_amdgcn_readfirstlane(ed[t+3]);
        float v0 = y[(size_t)s0 * HID + lane];
        float v1 = y[(size_t)s1 * HID + lane];
        float v2 = y[(size_t)s2 * HID + lane];
        float v3 = y[(size_t)s3 * HID + lane];
        acc += (v0 + v1) + (v2 + v3);
    }
    for (; t < n1; ++t) {
        int s = __builtin_amdgcn_readfirstlane(ed[t]);
        acc += y[(size_t)s * HID + lane];
    }
    h[(size_t)node * HID + lane] = acc * dinv[node];
}

// ---------------------------------------------------------------- relu + mean-pool sums (batch sorted)
__global__ void k_pool(const float* __restrict__ h, const float* __restrict__ bias,
                       const int* __restrict__ batch, float* __restrict__ pooled) {
    const int NPT   = 16;
    const int hh    = threadIdx.x & 63;
    const int grp   = threadIdx.x >> 6;
    const int node0 = (blockIdx.x * 4 + grp) * NPT;
    float bsv = bias[hh];
    float acc = 0.f;
    int   cur = -1;
    for (int t = 0; t < NPT; ++t) {
        int node = node0 + t;
        if (node >= N_NODES) break;
        int   bg = batch[node];
        float v  = fmaxf(h[(size_t)node * HID + hh] + bsv, 0.f);
        if (bg != cur) {
            if (cur >= 0) atomicAdd(&pooled[cur * HID + hh], acc);
            cur = bg;
            acc = v;
        } else {
            acc += v;
        }
    }
    if (cur >= 0) atomicAdd(&pooled[cur * HID + hh], acc);
}

// ---------------------------------------------------------------- pooled/cnt @ Wfc + bfc
__global__ void k_out(const float* __restrict__ pooled, const int* __restrict__ gstart,
                      const float* __restrict__ Wfc, const float* __restrict__ bfc,
                      float* __restrict__ out) {
    int idx = blockIdx.x * blockDim.x + threadIdx.x;    // 2048 = 256*8
    int g = idx >> 3;
    int o = idx & 7;
    float inv = 1.f / fmaxf((float)(gstart[g + 1] - gstart[g]), 1.f);
    float acc = 0.f;
#pragma unroll
    for (int k = 0; k < HID; ++k) acc += pooled[g * HID + k] * Wfc[k * OUT_C + o];
    out[idx] = acc * inv + bfc[o];
}

// ---------------------------------------------------------------- launch
extern "C" void kernel_launch(void* const* d_in, const int* in_sizes, int n_in,
                              void* d_out, int out_size, void* d_ws, size_t ws_size,
                              hipStream_t stream) {
    const float* x     = (const float*)d_in[0];
    const int*   eidx  = (const int*)d_in[1];      // [2, E] flat
    const int*   batch = (const int*)d_in[2];
    const float* W     = (const float*)d_in[3];
    const float* b     = (const float*)d_in[4];
    const float* Wfc   = (const float*)d_in[5];
    const float* bfc   = (const float*)d_in[6];
    float*       out   = (float*)d_out;

    const int* row = eidx;            // src
    const int* col = eidx + N_EDGES;  // dst

    // ---- workspace layout ----
    float* y      = (float*)d_ws;                         // N*HID
    float* h      = y + (size_t)N_NODES * HID;            // N*HID
    int*   part   = (int*)h;                              // NBH*NPK ints, aliases h (dead before gather)
    float* dinv   = h + (size_t)N_NODES * HID;            // NBIN
    float* pooled = dinv + NBIN;                          // NUM_G*HID
    int*   hist   = (int*)(pooled + NUM_G * HID);         // NBIN
    int*   nstart = hist + NBIN;                          // NBIN+4
    int*   tmp    = nstart + NBIN + 4;                    // NBIN
    int*   blkSum = tmp + NBIN;                           // 256
    int*   gstart = blkSum + 256;                         // 257
    int*   ed     = gstart + 260;                         // E

    k_initcnt<<<(NUM_G * HID + 255) / 256, 256, 0, stream>>>(pooled, batch, gstart);
    k_histB <<<NBH * NQ_H, 256, 0, stream>>>(col, part);
    k_red   <<<(NPK + 255) / 256, 256, 0, stream>>>(part, hist, dinv);
    k_scanA <<<NB_SCAN, 256, 0, stream>>>(hist, tmp, blkSum);
    k_scanB <<<1, 256, 0, stream>>>(blkSum);
    k_scanC <<<NB_SCAN, 256, 0, stream>>>(tmp, blkSum, nstart);
    k_scat2 <<<NBH * NQ_S, 256, 0, stream>>>(row, col, part, nstart, ed);
    k_lin   <<<(N_NODES + 63) / 64, 256, 0, stream>>>(x, W, dinv, y);
    k_gather<<<(N_NODES + 3) / 4, 256, 0, stream>>>(ed, nstart, dinv, y, h);
    k_pool  <<<(N_NODES + 63) / 64, 256, 0, stream>>>(h, b, batch, pooled);
    k_out   <<<8, 256, 0, stream>>>(pooled, gstart, Wfc, bfc, out);
}

// Round 5
// 114.227 us; speedup vs baseline: 2.9948x; 1.2496x over previous
//
#include <hip/hip_runtime.h>
#include <stdint.h>

#define N_NODES 50000
#define N_EDGES 800000
#define IN_C    128
#define HID     64
#define NUM_G   256
#define OUT_C   8

#define NBH   64                 // edge-ranges
#define ES    (N_EDGES / NBH)    // 12500 edges per range (ES*4 bytes, 16B aligned)
#define NBIN  50048              // padded bin count (even)
#define NPK   (NBIN / 2)         // 25024 packed u16-pair ints
#define NB_SCAN ((NBIN + 255) / 256)   // 196

#define NQ_H   4                 // histogram bin-quarters
#define BINS_H (NBIN / NQ_H)     // 12512 bins per hist block
#define PK_H   (BINS_H / 2)      // 6256 packed ints (25 KB LDS)
#define NQ_S   8                 // scatter bin-eighths
#define BINS_S (NBIN / NQ_S)     // 6256 bins per scat block (25 KB LDS)

__device__ __forceinline__ void gload_lds16(const void* g, void* l) {
    __builtin_amdgcn_global_load_lds(
        (const __attribute__((address_space(1))) unsigned int*)g,
        (__attribute__((address_space(3))) unsigned int*)l, 16, 0, 0);
}

// ---------------------------------------------------------------- LDS histogram: 64 ranges x 4 bin-quarters
__global__ __launch_bounds__(256) void k_histB(const int* __restrict__ col,
                                               int* __restrict__ part) {
    __shared__ int lh[PK_H];                 // 25 KB
    const int tid = threadIdx.x;
    const int r = blockIdx.x >> 2;
    const int q = blockIdx.x & 3;
    const int q0 = q * BINS_H;
    for (int i = tid; i < PK_H; i += 256) lh[i] = 0;
    __syncthreads();
    const int4* col4 = (const int4*)(col + r * ES);
#pragma unroll 2
    for (int j4 = tid; j4 < ES / 4; j4 += 256) {
        int4 c = col4[j4];
        unsigned d0 = (unsigned)(c.x - q0), d1 = (unsigned)(c.y - q0);
        unsigned d2 = (unsigned)(c.z - q0), d3 = (unsigned)(c.w - q0);
        if (d0 < BINS_H) atomicAdd(&lh[d0 >> 1], 1 << ((d0 & 1) * 16));
        if (d1 < BINS_H) atomicAdd(&lh[d1 >> 1], 1 << ((d1 & 1) * 16));
        if (d2 < BINS_H) atomicAdd(&lh[d2 >> 1], 1 << ((d2 & 1) * 16));
        if (d3 < BINS_H) atomicAdd(&lh[d3 >> 1], 1 << ((d3 & 1) * 16));
    }
    __syncthreads();
    int* dst = part + r * NPK + q * PK_H;
    for (int i = tid; i < PK_H; i += 256) dst[i] = lh[i];
}

// ---------------------------------------------------------------- reduce partials -> deg; part becomes blockbase; dinv fused
__global__ void k_red(int* __restrict__ part, int* __restrict__ hist,
                      float* __restrict__ dinv) {
    int t = blockIdx.x * 256 + threadIdx.x;
    if (t >= NPK) return;
    int s0 = 0, s1 = 0;
    int idx = t;
#pragma unroll 4
    for (int b = 0; b < NBH; ++b, idx += NPK) {
        int v = part[idx];
        part[idx] = s0 | (s1 << 16);          // exclusive per-range offset
        s0 += v & 0xffff;
        s1 += (v >> 16) & 0xffff;
    }
    ((int2*)hist)[t]   = make_int2(s0, s1);
    ((float2*)dinv)[t] = make_float2(rsqrtf((float)(s0 + 1)),
                                     rsqrtf((float)(s1 + 1)));
}

// ---------------------------------------------------------------- scan (3 kernels) over NBIN
__global__ void k_scanA(const int* __restrict__ hist, int* __restrict__ tmp,
                        int* __restrict__ blkSum) {
    __shared__ int s[256];
    int tid = threadIdx.x;
    int i = blockIdx.x * 256 + tid;
    int v = (i < NBIN) ? hist[i] : 0;
    s[tid] = v;
    __syncthreads();
    int acc = v;
#pragma unroll
    for (int off = 1; off < 256; off <<= 1) {
        int t = (tid >= off) ? s[tid - off] : 0;
        __syncthreads();
        acc += t;
        s[tid] = acc;
        __syncthreads();
    }
    if (i < NBIN) tmp[i] = acc - v;
    if (tid == 255) blkSum[blockIdx.x] = acc;
}

// single block: scan blkSums + compute graph boundaries (batch sorted)
__global__ void k_scanB(int* __restrict__ blkSum, const int* __restrict__ batch,
                        int* __restrict__ gstart) {
    __shared__ int s[256];
    int tid = threadIdx.x;
    int v = (tid < NB_SCAN) ? blkSum[tid] : 0;
    s[tid] = v;
    __syncthreads();
    int acc = v;
#pragma unroll
    for (int off = 1; off < 256; off <<= 1) {
        int t = (tid >= off) ? s[tid - off] : 0;
        __syncthreads();
        acc += t;
        s[tid] = acc;
        __syncthreads();
    }
    blkSum[tid] = acc - v;
    // graph boundaries: gstart[g] = first node with batch >= g
    {
        int lo = 0, hi = N_NODES;
        while (lo < hi) {
            int mid = (lo + hi) >> 1;
            if (batch[mid] < tid) lo = mid + 1; else hi = mid;
        }
        gstart[tid] = lo;
        if (tid == 0) gstart[NUM_G] = N_NODES;
    }
}

__global__ void k_scanC(const int* __restrict__ tmp, const int* __restrict__ blkOff,
                        int* __restrict__ nstart, float* __restrict__ pooled) {
    int i = blockIdx.x * 256 + threadIdx.x;
    if (i < NBIN) nstart[i] = tmp[i] + blkOff[blockIdx.x];
    if (i < NUM_G * HID) pooled[i] = 0.f;
}

// ---------------------------------------------------------------- scatter: 64 ranges x 8 bin-eighths, LDS cursors
__global__ __launch_bounds__(256) void k_scat2(const int* __restrict__ row,
                                               const int* __restrict__ col,
                                               const int* __restrict__ part,
                                               const int* __restrict__ nstart,
                                               int* __restrict__ ed) {
    __shared__ int lc[BINS_S];               // 25 KB
    const int tid = threadIdx.x;
    const int r = blockIdx.x >> 3;
    const int q = blockIdx.x & 7;
    const int q0 = q * BINS_S;
    for (int i = tid; i < BINS_S; i += 256) {
        int bin = q0 + i;
        int bb = part[r * NPK + (bin >> 1)];
        int off = (i & 1) ? ((bb >> 16) & 0xffff) : (bb & 0xffff);
        lc[i] = nstart[bin] + off;
    }
    __syncthreads();
    const int4* col4 = (const int4*)(col + r * ES);
    const int4* row4 = (const int4*)(row + r * ES);
#pragma unroll 2
    for (int j4 = tid; j4 < ES / 4; j4 += 256) {
        int4 c = col4[j4];
        int4 s = row4[j4];
        unsigned d0 = (unsigned)(c.x - q0), d1 = (unsigned)(c.y - q0);
        unsigned d2 = (unsigned)(c.z - q0), d3 = (unsigned)(c.w - q0);
        if (d0 < BINS_S) ed[atomicAdd(&lc[d0], 1)] = s.x;
        if (d1 < BINS_S) ed[atomicAdd(&lc[d1], 1)] = s.y;
        if (d2 < BINS_S) ed[atomicAdd(&lc[d2], 1)] = s.z;
        if (d3 < BINS_S) ed[atomicAdd(&lc[d3], 1)] = s.w;
    }
}

// ---------------------------------------------------------------- y = (x @ W) * dinv[row]  (64x64 tile, 4x4/thread)
__global__ __launch_bounds__(256) void k_lin(const float* __restrict__ x,
                                             const float* __restrict__ W,
                                             const float* __restrict__ dinv,
                                             float* __restrict__ y) {
    __shared__ float xs[64 * IN_C];   // 32 KB
    __shared__ float Ws[IN_C * HID];  // 32 KB
    const int tid = threadIdx.x;
    const size_t row0 = (size_t)blockIdx.x * 64;
    const int ln = tid & 63, wv = tid >> 6;

    {   // stage W via global_load_lds (32 chunks of 1 KB)
        const char* wsrc = (const char*)W;
#pragma unroll
        for (int it = 0; it < 8; ++it) {
            int c = wv * 8 + it;
            gload_lds16(wsrc + c * 1024 + ln * 16, (char*)Ws + c * 1024);
        }
    }
    if (row0 + 64 <= N_NODES) {
        const char* gsrc = (const char*)(x + row0 * IN_C);
#pragma unroll
        for (int it = 0; it < 8; ++it) {
            int c = wv * 8 + it;
            gload_lds16(gsrc + c * 1024 + ln * 16, (char*)xs + c * 1024);
        }
    } else {
        const float4* src = (const float4*)(x + row0 * IN_C);
        for (int i4 = tid; i4 < 2048; i4 += 256) {
            int r = i4 >> 5;
            float4 v = make_float4(0.f, 0.f, 0.f, 0.f);
            if (row0 + r < N_NODES) v = src[i4];
            ((float4*)xs)[i4] = v;
        }
    }
    __syncthreads();

    const int ty = tid >> 4, tx = tid & 15;
    const int r0 = ty * 4, c0 = tx * 4;
    float acc[4][4] = {};

#define AC(ai, kk) ((kk)==0 ? av##ai.x : (kk)==1 ? av##ai.y : (kk)==2 ? av##ai.z : av##ai.w)
#define ROWF(ai, kk, bv) \
    acc[ai][0] = fmaf(AC(ai,kk), bv.x, acc[ai][0]); \
    acc[ai][1] = fmaf(AC(ai,kk), bv.y, acc[ai][1]); \
    acc[ai][2] = fmaf(AC(ai,kk), bv.z, acc[ai][2]); \
    acc[ai][3] = fmaf(AC(ai,kk), bv.w, acc[ai][3]);
#define K4(kk, bv) ROWF(0,kk,bv) ROWF(1,kk,bv) ROWF(2,kk,bv) ROWF(3,kk,bv)

    for (int k = 0; k < IN_C; k += 4) {
        float4 av0 = *(const float4*)&xs[(r0+0)*IN_C + k];
        float4 av1 = *(const float4*)&xs[(r0+1)*IN_C + k];
        float4 av2 = *(const float4*)&xs[(r0+2)*IN_C + k];
        float4 av3 = *(const float4*)&xs[(r0+3)*IN_C + k];
        float4 bv0 = *(const float4*)&Ws[(k+0)*HID + c0];
        float4 bv1 = *(const float4*)&Ws[(k+1)*HID + c0];
        float4 bv2 = *(const float4*)&Ws[(k+2)*HID + c0];
        float4 bv3 = *(const float4*)&Ws[(k+3)*HID + c0];
        K4(0, bv0) K4(1, bv1) K4(2, bv2) K4(3, bv3)
    }
#undef K4
#undef ROWF
#undef AC

#pragma unroll
    for (int i = 0; i < 4; ++i) {
        size_t r = row0 + r0 + i;
        if (r < N_NODES) {
            float dv = dinv[r];
            float4 o = make_float4(acc[i][0]*dv, acc[i][1]*dv,
                                   acc[i][2]*dv, acc[i][3]*dv);
            *(float4*)&y[r * HID + c0] = o;
        }
    }
}

// ---------------------------------------------------------------- fused gather + relu + mean-pool sums
// wave = 8 consecutive nodes; h never materialized.
#define NPT 8
__global__ __launch_bounds__(256) void k_gpool(const int* __restrict__ ed,
                                               const int* __restrict__ nstart,
                                               const float* __restrict__ dinv,
                                               const float* __restrict__ y,
                                               const int* __restrict__ batch,
                                               const float* __restrict__ bias,
                                               float* __restrict__ pooled) {
    const int lane  = threadIdx.x & 63;
    const int node0 = (blockIdx.x * 4 + (threadIdx.x >> 6)) * NPT;
    if (node0 >= N_NODES) return;
    const float bsv = bias[lane];
    float pacc = 0.f;
    int   cur  = -1;
#pragma unroll 1
    for (int t0 = 0; t0 < NPT; ++t0) {
        int node = node0 + t0;
        if (node >= N_NODES) break;
        const int n0 = nstart[node], n1 = nstart[node + 1];
        float acc = y[(size_t)node * HID + lane];   // self-loop term
        int t = n0;
        for (; t + 4 <= n1; t += 4) {
            int s0 = __builtin_amdgcn_readfirstlane(ed[t]);
            int s1 = __builtin_amdgcn_readfirstlane(ed[t+1]);
            int s2 = __builtin_amdgcn_readfirstlane(ed[t+2]);
            int s3 = __builtin_amdgcn_readfirstlane(ed[t+3]);
            float v0 = y[(size_t)s0 * HID + lane];
            float v1 = y[(size_t)s1 * HID + lane];
            float v2 = y[(size_t)s2 * HID + lane];
            float v3 = y[(size_t)s3 * HID + lane];
            acc += (v0 + v1) + (v2 + v3);
        }
        for (; t < n1; ++t) {
            int s = __builtin_amdgcn_readfirstlane(ed[t]);
            acc += y[(size_t)s * HID + lane];
        }
        float hv = fmaxf(acc * dinv[node] + bsv, 0.f);
        int bg = batch[node];
        if (bg != cur) {
            if (cur >= 0) atomicAdd(&pooled[cur * HID + lane], pacc);
            cur  = bg;
            pacc = hv;
        } else {
            pacc += hv;
        }
    }
    if (cur >= 0) atomicAdd(&pooled[cur * HID + lane], pacc);
}

// ---------------------------------------------------------------- pooled/cnt @ Wfc + bfc
__global__ void k_out(const float* __restrict__ pooled, const int* __restrict__ gstart,
                      const float* __restrict__ Wfc, const float* __restrict__ bfc,
                      float* __restrict__ out) {
    int idx = blockIdx.x * blockDim.x + threadIdx.x;    // 2048 = 256*8
    int g = idx >> 3;
    int o = idx & 7;
    float inv = 1.f / fmaxf((float)(gstart[g + 1] - gstart[g]), 1.f);
    float acc = 0.f;
#pragma unroll
    for (int k = 0; k < HID; ++k) acc += pooled[g * HID + k] * Wfc[k * OUT_C + o];
    out[idx] = acc * inv + bfc[o];
}

// ---------------------------------------------------------------- launch
extern "C" void kernel_launch(void* const* d_in, const int* in_sizes, int n_in,
                              void* d_out, int out_size, void* d_ws, size_t ws_size,
                              hipStream_t stream) {
    const float* x     = (const float*)d_in[0];
    const int*   eidx  = (const int*)d_in[1];      // [2, E] flat
    const int*   batch = (const int*)d_in[2];
    const float* W     = (const float*)d_in[3];
    const float* b     = (const float*)d_in[4];
    const float* Wfc   = (const float*)d_in[5];
    const float* bfc   = (const float*)d_in[6];
    float*       out   = (float*)d_out;

    const int* row = eidx;            // src
    const int* col = eidx + N_EDGES;  // dst

    // ---- workspace layout ----
    float* y      = (float*)d_ws;                         // N*HID (12.8 MB)
    int*   part   = (int*)y;                              // NBH*NPK ints — aliases y; dead before k_lin runs
    float* dinv   = y + (size_t)N_NODES * HID;            // NBIN
    float* pooled = dinv + NBIN;                          // NUM_G*HID
    int*   hist   = (int*)(pooled + NUM_G * HID);         // NBIN
    int*   nstart = hist + NBIN;                          // NBIN+4
    int*   tmp    = nstart + NBIN + 4;                    // NBIN
    int*   blkSum = tmp + NBIN;                           // 256
    int*   gstart = blkSum + 256;                         // 257
    int*   ed     = gstart + 260;                         // E

    k_histB <<<NBH * NQ_H, 256, 0, stream>>>(col, part);
    k_red   <<<(NPK + 255) / 256, 256, 0, stream>>>(part, hist, dinv);
    k_scanA <<<NB_SCAN, 256, 0, stream>>>(hist, tmp, blkSum);
    k_scanB <<<1, 256, 0, stream>>>(blkSum, batch, gstart);
    k_scanC <<<NB_SCAN, 256, 0, stream>>>(tmp, blkSum, nstart, pooled);
    k_scat2 <<<NBH * NQ_S, 256, 0, stream>>>(row, col, part, nstart, ed);
    k_lin   <<<(N_NODES + 63) / 64, 256, 0, stream>>>(x, W, dinv, y);   // overwrites part (dead)
    k_gpool <<<(N_NODES + 4 * NPT - 1) / (4 * NPT), 256, 0, stream>>>(ed, nstart, dinv, y, batch, b, pooled);
    k_out   <<<8, 256, 0, stream>>>(pooled, gstart, Wfc, bfc, out);
}

// Round 6
// 104.862 us; speedup vs baseline: 3.2623x; 1.0893x over previous
//
#include <hip/hip_runtime.h>
#include <stdint.h>

#define N_NODES 50000
#define N_EDGES 800000
#define IN_C    128
#define HID     64
#define NUM_G   256
#define OUT_C   8

#define NBH   64                 // edge-ranges
#define ES    (N_EDGES / NBH)    // 12500 edges per range
#define NBIN  50048              // padded bin count (even)
#define NPK   (NBIN / 2)         // 25024 packed u16-pair ints

#define NQ_H   4                 // histogram bin-quarters
#define BINS_H (NBIN / NQ_H)     // 12512 bins per hist block
#define PK_H   (BINS_H / 2)      // 6256 packed ints (25 KB LDS)
#define NQ_S   8                 // scatter bin-eighths
#define BINS_S (NBIN / NQ_S)     // 6256 bins per scat block (25 KB LDS)

#define NBLK_CSR 98              // ceil(NPK/256)

__device__ __forceinline__ void gload_lds16(const void* g, void* l) {
    __builtin_amdgcn_global_load_lds(
        (const __attribute__((address_space(1))) unsigned int*)g,
        (__attribute__((address_space(3))) unsigned int*)l, 16, 0, 0);
}

__device__ __forceinline__ unsigned short f2bf(float f) {
    union { float f; unsigned u; } v; v.f = f;
    unsigned r = v.u + 0x7fff + ((v.u >> 16) & 1);   // RNE
    return (unsigned short)(r >> 16);
}
__device__ __forceinline__ float bf2f(unsigned short u) {
    union { unsigned u; float f; } v; v.u = ((unsigned)u) << 16;
    return v.f;
}

// ---------------------------------------------------------------- LDS histogram: 64 ranges x 4 bin-quarters
__global__ __launch_bounds__(256) void k_histB(const int* __restrict__ col,
                                               int* __restrict__ part,
                                               int* __restrict__ doneCnt) {
    __shared__ int lh[PK_H];                 // 25 KB
    const int tid = threadIdx.x;
    if (blockIdx.x == 0 && tid == 0)
        __hip_atomic_store(doneCnt, 0, __ATOMIC_RELAXED, __HIP_MEMORY_SCOPE_AGENT);
    const int r = blockIdx.x >> 2;
    const int q = blockIdx.x & 3;
    const int q0 = q * BINS_H;
    for (int i = tid; i < PK_H; i += 256) lh[i] = 0;
    __syncthreads();
    const int4* col4 = (const int4*)(col + r * ES);
#pragma unroll 2
    for (int j4 = tid; j4 < ES / 4; j4 += 256) {
        int4 c = col4[j4];
        unsigned d0 = (unsigned)(c.x - q0), d1 = (unsigned)(c.y - q0);
        unsigned d2 = (unsigned)(c.z - q0), d3 = (unsigned)(c.w - q0);
        if (d0 < BINS_H) atomicAdd(&lh[d0 >> 1], 1 << ((d0 & 1) * 16));
        if (d1 < BINS_H) atomicAdd(&lh[d1 >> 1], 1 << ((d1 & 1) * 16));
        if (d2 < BINS_H) atomicAdd(&lh[d2 >> 1], 1 << ((d2 & 1) * 16));
        if (d3 < BINS_H) atomicAdd(&lh[d3 >> 1], 1 << ((d3 & 1) * 16));
    }
    __syncthreads();
    int* dst = part + r * NPK + q * PK_H;
    for (int i = tid; i < PK_H; i += 256) dst[i] = lh[i];
}

// ---------------------------------------------------------------- fused: reduce + global scan + nstart + dinv + gstart + pooled-init
// 98 blocks, all co-resident (<< 256 CUs). Publish-aggregate then all-wait.
__global__ __launch_bounds__(256) void k_csr(int* __restrict__ part,
                                             float* __restrict__ dinv,
                                             int* __restrict__ nstart,
                                             const int* __restrict__ batch,
                                             int* __restrict__ gstart,
                                             float* __restrict__ pooled,
                                             int* __restrict__ agg,
                                             int* __restrict__ doneCnt) {
    __shared__ int sScan[256];
    __shared__ int sAgg[NBLK_CSR];
    __shared__ int sPrefix;
    const int tid = threadIdx.x;
    const int b   = blockIdx.x;
    const int t   = b * 256 + tid;
    const bool valid = t < NPK;

    int s0 = 0, s1 = 0;
    if (valid) {
        int idx = t;
#pragma unroll 4
        for (int r = 0; r < NBH; ++r, idx += NPK) {
            int v = part[idx];
            part[idx] = s0 | (s1 << 16);          // exclusive per-range offset
            s0 += v & 0xffff;
            s1 += (v >> 16) & 0xffff;
        }
        ((float2*)dinv)[t] = make_float2(rsqrtf((float)(s0 + 1)),
                                         rsqrtf((float)(s1 + 1)));
    }

    // block-level exclusive scan of pair sums
    int ps = s0 + s1;
    sScan[tid] = ps;
    __syncthreads();
    int acc = ps;
#pragma unroll
    for (int off = 1; off < 256; off <<= 1) {
        int tv = (tid >= off) ? sScan[tid - off] : 0;
        __syncthreads();
        acc += tv;
        sScan[tid] = acc;
        __syncthreads();
    }
    const int excl  = acc - ps;
    const int total = sScan[255];

    // publish aggregate, wait for all
    if (tid == 0) {
        __hip_atomic_store(&agg[b], total, __ATOMIC_RELAXED, __HIP_MEMORY_SCOPE_AGENT);
        __hip_atomic_fetch_add(doneCnt, 1, __ATOMIC_RELEASE, __HIP_MEMORY_SCOPE_AGENT);
        while (__hip_atomic_load(doneCnt, __ATOMIC_ACQUIRE, __HIP_MEMORY_SCOPE_AGENT) < NBLK_CSR)
            __builtin_amdgcn_s_sleep(1);
    }
    __syncthreads();
    if (tid < NBLK_CSR)
        sAgg[tid] = __hip_atomic_load(&agg[tid], __ATOMIC_RELAXED, __HIP_MEMORY_SCOPE_AGENT);
    __syncthreads();
    if (tid == 0) {
        int p = 0;
        for (int j = 0; j < b; ++j) p += sAgg[j];
        sPrefix = p;
    }
    __syncthreads();

    if (valid) {
        int base = sPrefix + excl;
        ((int2*)nstart)[t] = make_int2(base, base + s0);
    }
    // graph boundaries (batch sorted) + pooled zero-init
    if (t <= NUM_G) {
        int lo = 0, hi = N_NODES;
        while (lo < hi) {
            int mid = (lo + hi) >> 1;
            if (batch[mid] < t) lo = mid + 1; else hi = mid;
        }
        gstart[t] = lo;
    }
    if (t < NUM_G * HID) pooled[t] = 0.f;
}

// ---------------------------------------------------------------- scatter: 64 ranges x 8 bin-eighths, LDS cursors
__global__ __launch_bounds__(256) void k_scat2(const int* __restrict__ row,
                                               const int* __restrict__ col,
                                               const int* __restrict__ part,
                                               const int* __restrict__ nstart,
                                               int* __restrict__ ed) {
    __shared__ int lc[BINS_S];               // 25 KB
    const int tid = threadIdx.x;
    const int r = blockIdx.x >> 3;
    const int q = blockIdx.x & 7;
    const int q0 = q * BINS_S;
    for (int i = tid; i < BINS_S; i += 256) {
        int bin = q0 + i;
        int bb = part[r * NPK + (bin >> 1)];
        int off = (i & 1) ? ((bb >> 16) & 0xffff) : (bb & 0xffff);
        lc[i] = nstart[bin] + off;
    }
    __syncthreads();
    const int4* col4 = (const int4*)(col + r * ES);
    const int4* row4 = (const int4*)(row + r * ES);
#pragma unroll 2
    for (int j4 = tid; j4 < ES / 4; j4 += 256) {
        int4 c = col4[j4];
        int4 s = row4[j4];
        unsigned d0 = (unsigned)(c.x - q0), d1 = (unsigned)(c.y - q0);
        unsigned d2 = (unsigned)(c.z - q0), d3 = (unsigned)(c.w - q0);
        if (d0 < BINS_S) ed[atomicAdd(&lc[d0], 1)] = s.x;
        if (d1 < BINS_S) ed[atomicAdd(&lc[d1], 1)] = s.y;
        if (d2 < BINS_S) ed[atomicAdd(&lc[d2], 1)] = s.z;
        if (d3 < BINS_S) ed[atomicAdd(&lc[d3], 1)] = s.w;
    }
}

// ---------------------------------------------------------------- y = bf16((x @ W) * dinv[row])  (64x64 tile, 4x4/thread)
__global__ __launch_bounds__(256) void k_lin(const float* __restrict__ x,
                                             const float* __restrict__ W,
                                             const float* __restrict__ dinv,
                                             unsigned short* __restrict__ yb) {
    __shared__ float xs[64 * IN_C];   // 32 KB
    __shared__ float Ws[IN_C * HID];  // 32 KB
    const int tid = threadIdx.x;
    const size_t row0 = (size_t)blockIdx.x * 64;
    const int ln = tid & 63, wv = tid >> 6;

    {   // stage W via global_load_lds (32 chunks of 1 KB)
        const char* wsrc = (const char*)W;
#pragma unroll
        for (int it = 0; it < 8; ++it) {
            int c = wv * 8 + it;
            gload_lds16(wsrc + c * 1024 + ln * 16, (char*)Ws + c * 1024);
        }
    }
    if (row0 + 64 <= N_NODES) {
        const char* gsrc = (const char*)(x + row0 * IN_C);
#pragma unroll
        for (int it = 0; it < 8; ++it) {
            int c = wv * 8 + it;
            gload_lds16(gsrc + c * 1024 + ln * 16, (char*)xs + c * 1024);
        }
    } else {
        const float4* src = (const float4*)(x + row0 * IN_C);
        for (int i4 = tid; i4 < 2048; i4 += 256) {
            int r = i4 >> 5;
            float4 v = make_float4(0.f, 0.f, 0.f, 0.f);
            if (row0 + r < N_NODES) v = src[i4];
            ((float4*)xs)[i4] = v;
        }
    }
    __syncthreads();

    const int ty = tid >> 4, tx = tid & 15;
    const int r0 = ty * 4, c0 = tx * 4;
    float acc[4][4] = {};

#define AC(ai, kk) ((kk)==0 ? av##ai.x : (kk)==1 ? av##ai.y : (kk)==2 ? av##ai.z : av##ai.w)
#define ROWF(ai, kk, bv) \
    acc[ai][0] = fmaf(AC(ai,kk), bv.x, acc[ai][0]); \
    acc[ai][1] = fmaf(AC(ai,kk), bv.y, acc[ai][1]); \
    acc[ai][2] = fmaf(AC(ai,kk), bv.z, acc[ai][2]); \
    acc[ai][3] = fmaf(AC(ai,kk), bv.w, acc[ai][3]);
#define K4(kk, bv) ROWF(0,kk,bv) ROWF(1,kk,bv) ROWF(2,kk,bv) ROWF(3,kk,bv)

    for (int k = 0; k < IN_C; k += 4) {
        float4 av0 = *(const float4*)&xs[(r0+0)*IN_C + k];
        float4 av1 = *(const float4*)&xs[(r0+1)*IN_C + k];
        float4 av2 = *(const float4*)&xs[(r0+2)*IN_C + k];
        float4 av3 = *(const float4*)&xs[(r0+3)*IN_C + k];
        float4 bv0 = *(const float4*)&Ws[(k+0)*HID + c0];
        float4 bv1 = *(const float4*)&Ws[(k+1)*HID + c0];
        float4 bv2 = *(const float4*)&Ws[(k+2)*HID + c0];
        float4 bv3 = *(const float4*)&Ws[(k+3)*HID + c0];
        K4(0, bv0) K4(1, bv1) K4(2, bv2) K4(3, bv3)
    }
#undef K4
#undef ROWF
#undef AC

#pragma unroll
    for (int i = 0; i < 4; ++i) {
        size_t r = row0 + r0 + i;
        if (r < N_NODES) {
            float dv = dinv[r];
            ushort4 o;
            o.x = f2bf(acc[i][0] * dv);
            o.y = f2bf(acc[i][1] * dv);
            o.z = f2bf(acc[i][2] * dv);
            o.w = f2bf(acc[i][3] * dv);
            *(ushort4*)&yb[r * HID + c0] = o;
        }
    }
}

// ---------------------------------------------------------------- fused gather + relu + mean-pool sums (bf16 y)
#define NPT 8
__global__ __launch_bounds__(256) void k_gpool(const int* __restrict__ ed,
                                               const int* __restrict__ nstart,
                                               const float* __restrict__ dinv,
                                               const unsigned short* __restrict__ yb,
                                               const int* __restrict__ batch,
                                               const float* __restrict__ bias,
                                               float* __restrict__ pooled) {
    const int lane  = threadIdx.x & 63;
    const int node0 = (blockIdx.x * 4 + (threadIdx.x >> 6)) * NPT;
    if (node0 >= N_NODES) return;
    const float bsv = bias[lane];
    float pacc = 0.f;
    int   cur  = -1;
#pragma unroll 1
    for (int t0 = 0; t0 < NPT; ++t0) {
        int node = node0 + t0;
        if (node >= N_NODES) break;
        const int n0 = nstart[node], n1 = nstart[node + 1];
        float acc = bf2f(yb[(size_t)node * HID + lane]);   // self-loop term
        int t = n0;
        for (; t + 8 <= n1; t += 8) {
            int s0 = __builtin_amdgcn_readfirstlane(ed[t]);
            int s1 = __builtin_amdgcn_readfirstlane(ed[t+1]);
            int s2 = __builtin_amdgcn_readfirstlane(ed[t+2]);
            int s3 = __builtin_amdgcn_readfirstlane(ed[t+3]);
            int s4 = __builtin_amdgcn_readfirstlane(ed[t+4]);
            int s5 = __builtin_amdgcn_readfirstlane(ed[t+5]);
            int s6 = __builtin_amdgcn_readfirstlane(ed[t+6]);
            int s7 = __builtin_amdgcn_readfirstlane(ed[t+7]);
            float v0 = bf2f(yb[(size_t)s0 * HID + lane]);
            float v1 = bf2f(yb[(size_t)s1 * HID + lane]);
            float v2 = bf2f(yb[(size_t)s2 * HID + lane]);
            float v3 = bf2f(yb[(size_t)s3 * HID + lane]);
            float v4 = bf2f(yb[(size_t)s4 * HID + lane]);
            float v5 = bf2f(yb[(size_t)s5 * HID + lane]);
            float v6 = bf2f(yb[(size_t)s6 * HID + lane]);
            float v7 = bf2f(yb[(size_t)s7 * HID + lane]);
            acc += ((v0 + v1) + (v2 + v3)) + ((v4 + v5) + (v6 + v7));
        }
        for (; t + 4 <= n1; t += 4) {
            int s0 = __builtin_amdgcn_readfirstlane(ed[t]);
            int s1 = __builtin_amdgcn_readfirstlane(ed[t+1]);
            int s2 = __builtin_amdgcn_readfirstlane(ed[t+2]);
            int s3 = __builtin_amdgcn_readfirstlane(ed[t+3]);
            float v0 = bf2f(yb[(size_t)s0 * HID + lane]);
            float v1 = bf2f(yb[(size_t)s1 * HID + lane]);
            float v2 = bf2f(yb[(size_t)s2 * HID + lane]);
            float v3 = bf2f(yb[(size_t)s3 * HID + lane]);
            acc += (v0 + v1) + (v2 + v3);
        }
        for (; t < n1; ++t) {
            int s = __builtin_amdgcn_readfirstlane(ed[t]);
            acc += bf2f(yb[(size_t)s * HID + lane]);
        }
        float hv = fmaxf(acc * dinv[node] + bsv, 0.f);
        int bg = batch[node];
        if (bg != cur) {
            if (cur >= 0) atomicAdd(&pooled[cur * HID + lane], pacc);
            cur  = bg;
            pacc = hv;
        } else {
            pacc += hv;
        }
    }
    if (cur >= 0) atomicAdd(&pooled[cur * HID + lane], pacc);
}

// ---------------------------------------------------------------- pooled/cnt @ Wfc + bfc
__global__ void k_out(const float* __restrict__ pooled, const int* __restrict__ gstart,
                      const float* __restrict__ Wfc, const float* __restrict__ bfc,
                      float* __restrict__ out) {
    int idx = blockIdx.x * blockDim.x + threadIdx.x;    // 2048 = 256*8
    int g = idx >> 3;
    int o = idx & 7;
    float inv = 1.f / fmaxf((float)(gstart[g + 1] - gstart[g]), 1.f);
    float acc = 0.f;
#pragma unroll
    for (int k = 0; k < HID; ++k) acc += pooled[g * HID + k] * Wfc[k * OUT_C + o];
    out[idx] = acc * inv + bfc[o];
}

// ---------------------------------------------------------------- launch
extern "C" void kernel_launch(void* const* d_in, const int* in_sizes, int n_in,
                              void* d_out, int out_size, void* d_ws, size_t ws_size,
                              hipStream_t stream) {
    const float* x     = (const float*)d_in[0];
    const int*   eidx  = (const int*)d_in[1];      // [2, E] flat
    const int*   batch = (const int*)d_in[2];
    const float* W     = (const float*)d_in[3];
    const float* b     = (const float*)d_in[4];
    const float* Wfc   = (const float*)d_in[5];
    const float* bfc   = (const float*)d_in[6];
    float*       out   = (float*)d_out;

    const int* row = eidx;            // src
    const int* col = eidx + N_EDGES;  // dst

    // ---- workspace layout ----
    char* p = (char*)d_ws;
    int*            part = (int*)p;            // NBH*NPK ints (6.406 MB) — dead after k_scat2
    unsigned short* yb   = (unsigned short*)p; // N*HID bf16 (6.4 MB), aliases part; written by k_lin
    p += (size_t)NBH * NPK * 4;                // 6,406,144 (16B-mult)
    float* dinv   = (float*)p;  p += (size_t)NBIN * 4;        // 200,192
    float* pooled = (float*)p;  p += (size_t)NUM_G * HID * 4; // 65,536
    int*   nstart = (int*)p;    p += (size_t)(NBIN + 4) * 4;  // 200,208
    int*   gstart = (int*)p;    p += 1040;                    // 257 ints padded
    int*   agg    = (int*)p;    p += 400;                     // 98 ints padded
    int*   doneCnt= (int*)p;    p += 16;
    int*   ed     = (int*)p;                                  // E ints

    k_histB <<<NBH * NQ_H, 256, 0, stream>>>(col, part, doneCnt);
    k_csr   <<<NBLK_CSR, 256, 0, stream>>>(part, dinv, nstart, batch, gstart, pooled, agg, doneCnt);
    k_scat2 <<<NBH * NQ_S, 256, 0, stream>>>(row, col, part, nstart, ed);
    k_lin   <<<(N_NODES + 63) / 64, 256, 0, stream>>>(x, W, dinv, yb);   // overwrites part (dead)
    k_gpool <<<(N_NODES + 4 * NPT - 1) / (4 * NPT), 256, 0, stream>>>(ed, nstart, dinv, yb, batch, b, pooled);
    k_out   <<<8, 256, 0, stream>>>(pooled, gstart, Wfc, bfc, out);
}

// Round 7
// 102.286 us; speedup vs baseline: 3.3444x; 1.0252x over previous
//
#include <hip/hip_runtime.h>
#include <stdint.h>

#define N_NODES 50000
#define N_EDGES 800000
#define IN_C    128
#define HID     64
#define NUM_G   256
#define OUT_C   8

#define NBH   64                 // edge-ranges
#define ES    (N_EDGES / NBH)    // 12500 edges per range
#define NBIN  50048              // padded bin count (even)
#define NPK   (NBIN / 2)         // 25024 packed u16-pair ints

#define NQ_H   4                 // histogram bin-quarters
#define BINS_H (NBIN / NQ_H)     // 12512 bins per hist block
#define PK_H   (BINS_H / 2)      // 6256 packed ints (25 KB LDS)
#define NQ_S   8                 // scatter bin-eighths
#define BINS_S (NBIN / NQ_S)     // 6256 bins per scat block (25 KB LDS)

#define NBLK_CSR 98              // ceil(NPK/256)

__device__ __forceinline__ void gload_lds16(const void* g, void* l) {
    __builtin_amdgcn_global_load_lds(
        (const __attribute__((address_space(1))) unsigned int*)g,
        (__attribute__((address_space(3))) unsigned int*)l, 16, 0, 0);
}

__device__ __forceinline__ unsigned short f2bf(float f) {
    union { float f; unsigned u; } v; v.f = f;
    unsigned r = v.u + 0x7fff + ((v.u >> 16) & 1);   // RNE
    return (unsigned short)(r >> 16);
}

// unpack uint2 (4 bf16) -> float4 via bit ops
__device__ __forceinline__ float4 bf4(uint2 u) {
    union { unsigned u; float f; } a, b, c, d;
    a.u = u.x << 16;
    b.u = u.x & 0xffff0000u;
    c.u = u.y << 16;
    d.u = u.y & 0xffff0000u;
    return make_float4(a.f, b.f, c.f, d.f);
}

// ---------------------------------------------------------------- LDS histogram: 64 ranges x 4 bin-quarters
__global__ __launch_bounds__(256) void k_histB(const int* __restrict__ col,
                                               int* __restrict__ part,
                                               int* __restrict__ doneCnt) {
    __shared__ int lh[PK_H];                 // 25 KB
    const int tid = threadIdx.x;
    if (blockIdx.x == 0 && tid == 0)
        __hip_atomic_store(doneCnt, 0, __ATOMIC_RELAXED, __HIP_MEMORY_SCOPE_AGENT);
    const int r = blockIdx.x >> 2;
    const int q = blockIdx.x & 3;
    const int q0 = q * BINS_H;
    for (int i = tid; i < PK_H; i += 256) lh[i] = 0;
    __syncthreads();
    const int4* col4 = (const int4*)(col + r * ES);
#pragma unroll 2
    for (int j4 = tid; j4 < ES / 4; j4 += 256) {
        int4 c = col4[j4];
        unsigned d0 = (unsigned)(c.x - q0), d1 = (unsigned)(c.y - q0);
        unsigned d2 = (unsigned)(c.z - q0), d3 = (unsigned)(c.w - q0);
        if (d0 < BINS_H) atomicAdd(&lh[d0 >> 1], 1 << ((d0 & 1) * 16));
        if (d1 < BINS_H) atomicAdd(&lh[d1 >> 1], 1 << ((d1 & 1) * 16));
        if (d2 < BINS_H) atomicAdd(&lh[d2 >> 1], 1 << ((d2 & 1) * 16));
        if (d3 < BINS_H) atomicAdd(&lh[d3 >> 1], 1 << ((d3 & 1) * 16));
    }
    __syncthreads();
    int* dst = part + r * NPK + q * PK_H;
    for (int i = tid; i < PK_H; i += 256) dst[i] = lh[i];
}

// ---------------------------------------------------------------- fused: reduce + global scan + nstart + dinv + gstart + pooled-init
__global__ __launch_bounds__(256) void k_csr(int* __restrict__ part,
                                             float* __restrict__ dinv,
                                             int* __restrict__ nstart,
                                             const int* __restrict__ batch,
                                             int* __restrict__ gstart,
                                             float* __restrict__ pooled,
                                             int* __restrict__ agg,
                                             int* __restrict__ doneCnt) {
    __shared__ int sScan[256];
    __shared__ int sAgg[NBLK_CSR];
    __shared__ int sPrefix;
    const int tid = threadIdx.x;
    const int b   = blockIdx.x;
    const int t   = b * 256 + tid;
    const bool valid = t < NPK;

    int s0 = 0, s1 = 0;
    if (valid) {
        int idx = t;
#pragma unroll 4
        for (int r = 0; r < NBH; ++r, idx += NPK) {
            int v = part[idx];
            part[idx] = s0 | (s1 << 16);          // exclusive per-range offset
            s0 += v & 0xffff;
            s1 += (v >> 16) & 0xffff;
        }
        ((float2*)dinv)[t] = make_float2(rsqrtf((float)(s0 + 1)),
                                         rsqrtf((float)(s1 + 1)));
    }

    int ps = s0 + s1;
    sScan[tid] = ps;
    __syncthreads();
    int acc = ps;
#pragma unroll
    for (int off = 1; off < 256; off <<= 1) {
        int tv = (tid >= off) ? sScan[tid - off] : 0;
        __syncthreads();
        acc += tv;
        sScan[tid] = acc;
        __syncthreads();
    }
    const int excl  = acc - ps;
    const int total = sScan[255];

    if (tid == 0) {
        __hip_atomic_store(&agg[b], total, __ATOMIC_RELAXED, __HIP_MEMORY_SCOPE_AGENT);
        __hip_atomic_fetch_add(doneCnt, 1, __ATOMIC_RELEASE, __HIP_MEMORY_SCOPE_AGENT);
        while (__hip_atomic_load(doneCnt, __ATOMIC_ACQUIRE, __HIP_MEMORY_SCOPE_AGENT) < NBLK_CSR)
            __builtin_amdgcn_s_sleep(1);
    }
    __syncthreads();
    if (tid < NBLK_CSR)
        sAgg[tid] = __hip_atomic_load(&agg[tid], __ATOMIC_RELAXED, __HIP_MEMORY_SCOPE_AGENT);
    __syncthreads();
    if (tid == 0) {
        int p = 0;
        for (int j = 0; j < b; ++j) p += sAgg[j];
        sPrefix = p;
    }
    __syncthreads();

    if (valid) {
        int base = sPrefix + excl;
        ((int2*)nstart)[t] = make_int2(base, base + s0);
    }
    if (t <= NUM_G) {
        int lo = 0, hi = N_NODES;
        while (lo < hi) {
            int mid = (lo + hi) >> 1;
            if (batch[mid] < t) lo = mid + 1; else hi = mid;
        }
        gstart[t] = lo;
    }
    if (t < NUM_G * HID) pooled[t] = 0.f;
}

// ---------------------------------------------------------------- scatter: 64 ranges x 8 bin-eighths, LDS cursors
__global__ __launch_bounds__(256) void k_scat2(const int* __restrict__ row,
                                               const int* __restrict__ col,
                                               const int* __restrict__ part,
                                               const int* __restrict__ nstart,
                                               int* __restrict__ ed) {
    __shared__ int lc[BINS_S];               // 25 KB
    const int tid = threadIdx.x;
    const int r = blockIdx.x >> 3;
    const int q = blockIdx.x & 7;
    const int q0 = q * BINS_S;
    for (int i = tid; i < BINS_S; i += 256) {
        int bin = q0 + i;
        int bb = part[r * NPK + (bin >> 1)];
        int off = (i & 1) ? ((bb >> 16) & 0xffff) : (bb & 0xffff);
        lc[i] = nstart[bin] + off;
    }
    __syncthreads();
    const int4* col4 = (const int4*)(col + r * ES);
    const int4* row4 = (const int4*)(row + r * ES);
#pragma unroll 2
    for (int j4 = tid; j4 < ES / 4; j4 += 256) {
        int4 c = col4[j4];
        int4 s = row4[j4];
        unsigned d0 = (unsigned)(c.x - q0), d1 = (unsigned)(c.y - q0);
        unsigned d2 = (unsigned)(c.z - q0), d3 = (unsigned)(c.w - q0);
        if (d0 < BINS_S) ed[atomicAdd(&lc[d0], 1)] = s.x;
        if (d1 < BINS_S) ed[atomicAdd(&lc[d1], 1)] = s.y;
        if (d2 < BINS_S) ed[atomicAdd(&lc[d2], 1)] = s.z;
        if (d3 < BINS_S) ed[atomicAdd(&lc[d3], 1)] = s.w;
    }
}

// ---------------------------------------------------------------- y = bf16((x @ W) * dinv[row])  (64x64 tile, 4x4/thread)
__global__ __launch_bounds__(256) void k_lin(const float* __restrict__ x,
                                             const float* __restrict__ W,
                                             const float* __restrict__ dinv,
                                             unsigned short* __restrict__ yb) {
    __shared__ float xs[64 * IN_C];   // 32 KB
    __shared__ float Ws[IN_C * HID];  // 32 KB
    const int tid = threadIdx.x;
    const size_t row0 = (size_t)blockIdx.x * 64;
    const int ln = tid & 63, wv = tid >> 6;

    {
        const char* wsrc = (const char*)W;
#pragma unroll
        for (int it = 0; it < 8; ++it) {
            int c = wv * 8 + it;
            gload_lds16(wsrc + c * 1024 + ln * 16, (char*)Ws + c * 1024);
        }
    }
    if (row0 + 64 <= N_NODES) {
        const char* gsrc = (const char*)(x + row0 * IN_C);
#pragma unroll
        for (int it = 0; it < 8; ++it) {
            int c = wv * 8 + it;
            gload_lds16(gsrc + c * 1024 + ln * 16, (char*)xs + c * 1024);
        }
    } else {
        const float4* src = (const float4*)(x + row0 * IN_C);
        for (int i4 = tid; i4 < 2048; i4 += 256) {
            int r = i4 >> 5;
            float4 v = make_float4(0.f, 0.f, 0.f, 0.f);
            if (row0 + r < N_NODES) v = src[i4];
            ((float4*)xs)[i4] = v;
        }
    }
    __syncthreads();

    const int ty = tid >> 4, tx = tid & 15;
    const int r0 = ty * 4, c0 = tx * 4;
    float acc[4][4] = {};

#define AC(ai, kk) ((kk)==0 ? av##ai.x : (kk)==1 ? av##ai.y : (kk)==2 ? av##ai.z : av##ai.w)
#define ROWF(ai, kk, bv) \
    acc[ai][0] = fmaf(AC(ai,kk), bv.x, acc[ai][0]); \
    acc[ai][1] = fmaf(AC(ai,kk), bv.y, acc[ai][1]); \
    acc[ai][2] = fmaf(AC(ai,kk), bv.z, acc[ai][2]); \
    acc[ai][3] = fmaf(AC(ai,kk), bv.w, acc[ai][3]);
#define K4(kk, bv) ROWF(0,kk,bv) ROWF(1,kk,bv) ROWF(2,kk,bv) ROWF(3,kk,bv)

    for (int k = 0; k < IN_C; k += 4) {
        float4 av0 = *(const float4*)&xs[(r0+0)*IN_C + k];
        float4 av1 = *(const float4*)&xs[(r0+1)*IN_C + k];
        float4 av2 = *(const float4*)&xs[(r0+2)*IN_C + k];
        float4 av3 = *(const float4*)&xs[(r0+3)*IN_C + k];
        float4 bv0 = *(const float4*)&Ws[(k+0)*HID + c0];
        float4 bv1 = *(const float4*)&Ws[(k+1)*HID + c0];
        float4 bv2 = *(const float4*)&Ws[(k+2)*HID + c0];
        float4 bv3 = *(const float4*)&Ws[(k+3)*HID + c0];
        K4(0, bv0) K4(1, bv1) K4(2, bv2) K4(3, bv3)
    }
#undef K4
#undef ROWF
#undef AC

#pragma unroll
    for (int i = 0; i < 4; ++i) {
        size_t r = row0 + r0 + i;
        if (r < N_NODES) {
            float dv = dinv[r];
            ushort4 o;
            o.x = f2bf(acc[i][0] * dv);
            o.y = f2bf(acc[i][1] * dv);
            o.z = f2bf(acc[i][2] * dv);
            o.w = f2bf(acc[i][3] * dv);
            *(ushort4*)&yb[r * HID + c0] = o;
        }
    }
}

// ---------------------------------------------------------------- fused gather + relu + mean-pool (4 edges per load instr)
// lane = (grp = l>>4 edge slot, sl = l&15 dim-quad). Each lane loads ushort4
// (4 dims) of edge-group grp's source row: 512 B / wave-instruction.
#define NPT 8
__global__ __launch_bounds__(256) void k_gpool(const int* __restrict__ ed,
                                               const int* __restrict__ nstart,
                                               const float* __restrict__ dinv,
                                               const unsigned short* __restrict__ yb,
                                               const int* __restrict__ batch,
                                               const float* __restrict__ bias,
                                               float* __restrict__ pooled) {
    const int lane = threadIdx.x & 63;
    const int grp  = lane >> 4;
    const int sl   = lane & 15;
    const int node0 = (blockIdx.x * 4 + (threadIdx.x >> 6)) * NPT;
    if (node0 >= N_NODES) return;
    const float4 b4 = *(const float4*)&bias[4 * sl];
    float4 pacc = make_float4(0.f, 0.f, 0.f, 0.f);
    int    cur  = -1;
#pragma unroll 1
    for (int t0 = 0; t0 < NPT; ++t0) {
        int node = node0 + t0;
        if (node >= N_NODES) break;
        const int n0 = nstart[node], n1 = nstart[node + 1];
        float4 facc = make_float4(0.f, 0.f, 0.f, 0.f);
        int t = n0 + grp;
        const int nfull8 = n0 + ((n1 - n0) & ~7);
        // unconditional 8-edge chunks (2 loads in flight)
#pragma unroll 1
        for (; t < nfull8; t += 8) {
            int srcA = ed[t];
            int srcB = ed[t + 4];
            uint2 ua = *(const uint2*)&yb[(size_t)srcA * HID + 4 * sl];
            uint2 ub = *(const uint2*)&yb[(size_t)srcB * HID + 4 * sl];
            float4 va = bf4(ua), vb = bf4(ub);
            facc.x += va.x + vb.x;
            facc.y += va.y + vb.y;
            facc.z += va.z + vb.z;
            facc.w += va.w + vb.w;
        }
        // tail: <8 edges remain -> at most 2 predicated group-strided steps
#pragma unroll
        for (int step = 0; step < 2; ++step) {
            bool act = t < n1;
            int tt = act ? t : 0;
            int src = ed[tt];
            uint2 u = *(const uint2*)&yb[(size_t)src * HID + 4 * sl];
            if (act) {
                float4 v = bf4(u);
                facc.x += v.x; facc.y += v.y; facc.z += v.z; facc.w += v.w;
            }
            t += 4;
        }
        // reduce across the 4 edge-groups (lanes ^16, ^32)
        facc.x += __shfl_xor(facc.x, 16, 64);
        facc.y += __shfl_xor(facc.y, 16, 64);
        facc.z += __shfl_xor(facc.z, 16, 64);
        facc.w += __shfl_xor(facc.w, 16, 64);
        facc.x += __shfl_xor(facc.x, 32, 64);
        facc.y += __shfl_xor(facc.y, 32, 64);
        facc.z += __shfl_xor(facc.z, 32, 64);
        facc.w += __shfl_xor(facc.w, 32, 64);
        // self-loop term + epilogue
        uint2 us = *(const uint2*)&yb[(size_t)node * HID + 4 * sl];
        float4 vs = bf4(us);
        float dv = dinv[node];
        float4 hv;
        hv.x = fmaxf((facc.x + vs.x) * dv + b4.x, 0.f);
        hv.y = fmaxf((facc.y + vs.y) * dv + b4.y, 0.f);
        hv.z = fmaxf((facc.z + vs.z) * dv + b4.z, 0.f);
        hv.w = fmaxf((facc.w + vs.w) * dv + b4.w, 0.f);
        int bg = batch[node];
        if (bg != cur) {
            if (cur >= 0 && grp == 0) {
                atomicAdd(&pooled[cur * HID + 4 * sl + 0], pacc.x);
                atomicAdd(&pooled[cur * HID + 4 * sl + 1], pacc.y);
                atomicAdd(&pooled[cur * HID + 4 * sl + 2], pacc.z);
                atomicAdd(&pooled[cur * HID + 4 * sl + 3], pacc.w);
            }
            cur  = bg;
            pacc = hv;
        } else {
            pacc.x += hv.x; pacc.y += hv.y; pacc.z += hv.z; pacc.w += hv.w;
        }
    }
    if (cur >= 0 && grp == 0) {
        atomicAdd(&pooled[cur * HID + 4 * sl + 0], pacc.x);
        atomicAdd(&pooled[cur * HID + 4 * sl + 1], pacc.y);
        atomicAdd(&pooled[cur * HID + 4 * sl + 2], pacc.z);
        atomicAdd(&pooled[cur * HID + 4 * sl + 3], pacc.w);
    }
}

// ---------------------------------------------------------------- pooled/cnt @ Wfc + bfc
__global__ void k_out(const float* __restrict__ pooled, const int* __restrict__ gstart,
                      const float* __restrict__ Wfc, const float* __restrict__ bfc,
                      float* __restrict__ out) {
    int idx = blockIdx.x * blockDim.x + threadIdx.x;    // 2048 = 256*8
    int g = idx >> 3;
    int o = idx & 7;
    float inv = 1.f / fmaxf((float)(gstart[g + 1] - gstart[g]), 1.f);
    float acc = 0.f;
#pragma unroll
    for (int k = 0; k < HID; ++k) acc += pooled[g * HID + k] * Wfc[k * OUT_C + o];
    out[idx] = acc * inv + bfc[o];
}

// ---------------------------------------------------------------- launch
extern "C" void kernel_launch(void* const* d_in, const int* in_sizes, int n_in,
                              void* d_out, int out_size, void* d_ws, size_t ws_size,
                              hipStream_t stream) {
    const float* x     = (const float*)d_in[0];
    const int*   eidx  = (const int*)d_in[1];      // [2, E] flat
    const int*   batch = (const int*)d_in[2];
    const float* W     = (const float*)d_in[3];
    const float* b     = (const float*)d_in[4];
    const float* Wfc   = (const float*)d_in[5];
    const float* bfc   = (const float*)d_in[6];
    float*       out   = (float*)d_out;

    const int* row = eidx;            // src
    const int* col = eidx + N_EDGES;  // dst

    // ---- workspace layout ----
    char* p = (char*)d_ws;
    int*            part = (int*)p;            // NBH*NPK ints (6.406 MB) — dead after k_scat2
    unsigned short* yb   = (unsigned short*)p; // N*HID bf16 (6.4 MB), aliases part; written by k_lin
    p += (size_t)NBH * NPK * 4;                // 6,406,144 (16B-mult)
    float* dinv   = (float*)p;  p += (size_t)NBIN * 4;        // 200,192
    float* pooled = (float*)p;  p += (size_t)NUM_G * HID * 4; // 65,536
    int*   nstart = (int*)p;    p += (size_t)(NBIN + 4) * 4;  // 200,208
    int*   gstart = (int*)p;    p += 1040;                    // 257 ints padded
    int*   agg    = (int*)p;    p += 400;                     // 98 ints padded
    int*   doneCnt= (int*)p;    p += 16;
    int*   ed     = (int*)p;                                  // E ints

    k_histB <<<NBH * NQ_H, 256, 0, stream>>>(col, part, doneCnt);
    k_csr   <<<NBLK_CSR, 256, 0, stream>>>(part, dinv, nstart, batch, gstart, pooled, agg, doneCnt);
    k_scat2 <<<NBH * NQ_S, 256, 0, stream>>>(row, col, part, nstart, ed);
    k_lin   <<<(N_NODES + 63) / 64, 256, 0, stream>>>(x, W, dinv, yb);   // overwrites part (dead)
    k_gpool <<<(N_NODES + 4 * NPT - 1) / (4 * NPT), 256, 0, stream>>>(ed, nstart, dinv, yb, batch, b, pooled);
    k_out   <<<8, 256, 0, stream>>>(pooled, gstart, Wfc, bfc, out);
}